// Round 1
// baseline (6638.873 us; speedup 1.0000x reference)
//
#include <hip/hip_runtime.h>

#define NN 100000
#define NE 800000
// D = 160, K = 320, F = 128

// ---------------------------------------------------------------- zero
__global__ __launch_bounds__(256) void k_zero(float4* __restrict__ p, int n4) {
  int i = blockIdx.x * 256 + threadIdx.x;
  if (i < n4) p[i] = make_float4(0.f, 0.f, 0.f, 0.f);
}

// ---------------------------------------------------------------- degree count
__global__ __launch_bounds__(256) void k_count(const int* __restrict__ ei,
                                               float* __restrict__ cnt) {
  int e = blockIdx.x * 256 + threadIdx.x;  // grid exact: 3125*256 = 800000
  atomicAdd(&cnt[ei[NE + e]], 1.0f);
}

// ---------------------------------------------------------------- encoder
// h[n,0:128] = relu(LN(x @ w_enc^T + b_enc)); h[n,128:160] = relu(LN(ts*w_time + b_time))
// block=256: 8 nodes per iter, thread t -> node slot t>>5, output dims (t&31)*4 .. +3
__global__ __launch_bounds__(256) void k_encode(
    const float* __restrict__ x, const float* __restrict__ tsp,
    const float* __restrict__ w_enc, const float* __restrict__ b_enc,
    const float* __restrict__ g_enc, const float* __restrict__ be_enc,
    const float* __restrict__ w_time, const float* __restrict__ b_time,
    const float* __restrict__ g_time, const float* __restrict__ be_time,
    float* __restrict__ h) {
  __shared__ float wT[128 * 132];  // wT[k*132+j] = w_enc[j,k]; stride 132 keeps b128 reads full-rate
  __shared__ float xsh[8 * 128];
  const int t = threadIdx.x;
  for (int idx = t; idx < 128 * 128; idx += 256) {
    int j = idx >> 7, k = idx & 127;
    wT[k * 132 + j] = w_enc[idx];
  }
  // time-LN closed form: v_d = w_d*ts + b_d -> mean = mw*ts+mb, var = A ts^2 + 2B ts + C
  float mw = 0.f, mb = 0.f;
  for (int d = 0; d < 32; ++d) { mw += w_time[d]; mb += b_time[d]; }
  mw *= (1.f / 32.f); mb *= (1.f / 32.f);
  float A = 0.f, B = 0.f, C = 0.f;
  for (int d = 0; d < 32; ++d) {
    float a = w_time[d] - mw, c = b_time[d] - mb;
    A = fmaf(a, a, A); B = fmaf(a, c, B); C = fmaf(c, c, C);
  }
  A *= (1.f / 32.f); B *= (1.f / 32.f); C *= (1.f / 32.f);

  const int jg = t & 31, j4 = jg * 4, slot = t >> 5;
  const float be0 = b_enc[j4], be1 = b_enc[j4 + 1], be2 = b_enc[j4 + 2], be3 = b_enc[j4 + 3];
  const float g0 = g_enc[j4], g1 = g_enc[j4 + 1], g2 = g_enc[j4 + 2], g3 = g_enc[j4 + 3];
  const float s0 = be_enc[j4], s1 = be_enc[j4 + 1], s2 = be_enc[j4 + 2], s3 = be_enc[j4 + 3];
  const float wtj = w_time[jg], btj = b_time[jg], gtj = g_time[jg], stj = be_time[jg];

  for (int it = 0; it < 25; ++it) {  // grid 500: 500*25*8 = 100000
    const int node0 = (blockIdx.x * 25 + it) * 8;
    __syncthreads();
    for (int q = t; q < 1024; q += 256) xsh[q] = x[node0 * 128 + q];
    __syncthreads();
    const int node = node0 + slot;
    float4 acc = make_float4(be0, be1, be2, be3);
#pragma unroll 8
    for (int k = 0; k < 128; ++k) {
      float xv = xsh[slot * 128 + k];
      float4 wv = *(const float4*)&wT[k * 132 + j4];
      acc.x = fmaf(wv.x, xv, acc.x); acc.y = fmaf(wv.y, xv, acc.y);
      acc.z = fmaf(wv.z, xv, acc.z); acc.w = fmaf(wv.w, xv, acc.w);
    }
    float s = acc.x + acc.y + acc.z + acc.w;
    float ss = fmaf(acc.x, acc.x, fmaf(acc.y, acc.y, fmaf(acc.z, acc.z, acc.w * acc.w)));
#pragma unroll
    for (int off = 1; off < 32; off <<= 1) { s += __shfl_xor(s, off); ss += __shfl_xor(ss, off); }
    const float m = s * (1.f / 128.f);
    const float var = ss * (1.f / 128.f) - m * m;
    const float rs = rsqrtf(var + 1e-5f);
    float4 y;
    y.x = fmaxf(fmaf((acc.x - m) * rs, g0, s0), 0.f);
    y.y = fmaxf(fmaf((acc.y - m) * rs, g1, s1), 0.f);
    y.z = fmaxf(fmaf((acc.z - m) * rs, g2, s2), 0.f);
    y.w = fmaxf(fmaf((acc.w - m) * rs, g3, s3), 0.f);
    *(float4*)&h[node * 160 + j4] = y;
    // time encoder: 32 lanes of this node each write one of dims 128..159
    const float tsv = tsp[node];
    const float mt = fmaf(mw, tsv, mb);
    const float vart = fmaf(fmaf(A, tsv, 2.f * B), tsv, C);
    const float rst = rsqrtf(vart + 1e-5f);
    const float v = fmaf(wtj, tsv, btj);
    h[node * 160 + 128 + jg] = fmaxf(fmaf((v - mt) * rst, gtj, stj), 0.f);
  }
}

// ---------------------------------------------------------------- edge message MLP + scatter
// block = 256 threads = 8 edge-groups(4 edges) x 32 j-groups(5 outs), 32 edges/block
__global__ __launch_bounds__(256) void k_edge(
    const float* __restrict__ h, const int* __restrict__ ei, const float* __restrict__ ew,
    const float* __restrict__ wm, const float* __restrict__ bm,
    const float* __restrict__ gm, const float* __restrict__ bem,
    float* __restrict__ msum) {
  __shared__ float ecat[32 * 324];   // [edge][320], pad 4
  __shared__ float wsh[160 * 36];    // K-tile [j][32], pad 4
  const int t = threadIdx.x;
  const int e0 = blockIdx.x * 32;    // grid exact: 25000*32 = 800000
  // stage ecat = [h[src], h[dst]] as float4
#pragma unroll
  for (int r = 0; r < 10; ++r) {
    int q = t + r * 256;             // 2560 = 32 edges * 80 float4
    int e = q / 80, o = q % 80;
    int eg_ = e0 + e;
    int node, oo;
    if (o < 40) { node = ei[eg_]; oo = o; } else { node = ei[NE + eg_]; oo = o - 40; }
    *(float4*)&ecat[e * 324 + o * 4] = *(const float4*)&h[node * 160 + oo * 4];
  }
  const int jg = t & 31, eg = t >> 5;
  float acc[4][5];
#pragma unroll
  for (int a = 0; a < 4; ++a)
#pragma unroll
    for (int b = 0; b < 5; ++b) acc[a][b] = 0.f;

  for (int kt = 0; kt < 10; ++kt) {
    __syncthreads();
#pragma unroll
    for (int r = 0; r < 20; ++r) {
      int q = t + r * 256;           // 5120 = 160*32
      int j = q >> 5, kk = q & 31;
      wsh[j * 36 + kk] = wm[j * 320 + kt * 32 + kk];
    }
    __syncthreads();
    const int kbase = kt * 32;
#pragma unroll
    for (int kq = 0; kq < 8; ++kq) {
      const int kl = kq * 4;
      float4 b[5];
#pragma unroll
      for (int i = 0; i < 5; ++i) b[i] = *(const float4*)&wsh[(jg + 32 * i) * 36 + kl];
#pragma unroll
      for (int ee = 0; ee < 4; ++ee) {
        float4 a = *(const float4*)&ecat[(eg * 4 + ee) * 324 + kbase + kl];
#pragma unroll
        for (int i = 0; i < 5; ++i)
          acc[ee][i] = fmaf(a.x, b[i].x, fmaf(a.y, b[i].y, fmaf(a.z, b[i].z, fmaf(a.w, b[i].w, acc[ee][i]))));
      }
    }
  }
  // epilogue: +bm, LN(160) via half-wave shuffle, *gm+bem, relu, *w_e, atomic scatter
#pragma unroll
  for (int ee = 0; ee < 4; ++ee) {
    const int e = e0 + eg * 4 + ee;
    float v[5], s = 0.f, ss = 0.f;
#pragma unroll
    for (int i = 0; i < 5; ++i) {
      v[i] = acc[ee][i] + bm[jg + 32 * i];
      s += v[i]; ss = fmaf(v[i], v[i], ss);
    }
#pragma unroll
    for (int off = 1; off < 32; off <<= 1) { s += __shfl_xor(s, off); ss += __shfl_xor(ss, off); }
    const float m = s * (1.f / 160.f);
    const float var = ss * (1.f / 160.f) - m * m;
    const float rs = rsqrtf(var + 1e-5f);
    const float we = ew[e];
    float* mrow = &msum[(size_t)ei[NE + e] * 160];
#pragma unroll
    for (int i = 0; i < 5; ++i) {
      int j = jg + 32 * i;
      float y = fmaxf(fmaf((v[i] - m) * rs, gm[j], bem[j]), 0.f) * we;
      atomicAdd(&mrow[j], y);
    }
  }
}

// ---------------------------------------------------------------- node update MLP + gate
__global__ __launch_bounds__(256) void k_update(
    float* __restrict__ h, const float* __restrict__ msum, const float* __restrict__ cnt,
    const float* __restrict__ wu, const float* __restrict__ bu,
    const float* __restrict__ gu, const float* __restrict__ beu,
    const float* __restrict__ wg, const float* __restrict__ bg) {
  __shared__ float insh[32 * 324];
  __shared__ float wsh[160 * 36];
  const int t = threadIdx.x;
  const int n0 = blockIdx.x * 32;    // grid exact: 3125*32 = 100000
#pragma unroll
  for (int r = 0; r < 10; ++r) {
    int q = t + r * 256;
    int nn = q / 80, o = q % 80;
    int node = n0 + nn;
    float4 v;
    if (o < 40) {
      v = *(const float4*)&h[node * 160 + o * 4];
    } else {
      float c = cnt[node];
      float ic = (c > 0.f) ? 1.f / (c + 1e-8f) : 0.f;
      v = *(const float4*)&msum[node * 160 + (o - 40) * 4];
      v.x *= ic; v.y *= ic; v.z *= ic; v.w *= ic;
    }
    *(float4*)&insh[nn * 324 + o * 4] = v;
  }
  __syncthreads();
  const int jg = t & 31, eg = t >> 5;
  const float bgv = bg[0];
  float tw[4];
#pragma unroll
  for (int ee = 0; ee < 4; ++ee) {
    const int nn = eg * 4 + ee;
    float gp = 0.f;
#pragma unroll
    for (int i = 0; i < 5; ++i) {
      int j = jg + 32 * i;
      gp = fmaf(wg[j], insh[nn * 324 + j], gp);
    }
#pragma unroll
    for (int off = 1; off < 32; off <<= 1) gp += __shfl_xor(gp, off);
    tw[ee] = 1.f / (1.f + expf(-(gp + bgv)));
  }
  float acc[4][5];
#pragma unroll
  for (int a = 0; a < 4; ++a)
#pragma unroll
    for (int b = 0; b < 5; ++b) acc[a][b] = 0.f;

  for (int kt = 0; kt < 10; ++kt) {
    __syncthreads();
#pragma unroll
    for (int r = 0; r < 20; ++r) {
      int q = t + r * 256;
      int j = q >> 5, kk = q & 31;
      wsh[j * 36 + kk] = wu[j * 320 + kt * 32 + kk];
    }
    __syncthreads();
    const int kbase = kt * 32;
#pragma unroll
    for (int kq = 0; kq < 8; ++kq) {
      const int kl = kq * 4;
      float4 b[5];
#pragma unroll
      for (int i = 0; i < 5; ++i) b[i] = *(const float4*)&wsh[(jg + 32 * i) * 36 + kl];
#pragma unroll
      for (int ee = 0; ee < 4; ++ee) {
        float4 a = *(const float4*)&insh[(eg * 4 + ee) * 324 + kbase + kl];
#pragma unroll
        for (int i = 0; i < 5; ++i)
          acc[ee][i] = fmaf(a.x, b[i].x, fmaf(a.y, b[i].y, fmaf(a.z, b[i].z, fmaf(a.w, b[i].w, acc[ee][i]))));
      }
    }
  }
#pragma unroll
  for (int ee = 0; ee < 4; ++ee) {
    const int nn = eg * 4 + ee;
    const int node = n0 + nn;
    float v[5], s = 0.f, ss = 0.f;
#pragma unroll
    for (int i = 0; i < 5; ++i) {
      v[i] = acc[ee][i] + bu[jg + 32 * i];
      s += v[i]; ss = fmaf(v[i], v[i], ss);
    }
#pragma unroll
    for (int off = 1; off < 32; off <<= 1) { s += __shfl_xor(s, off); ss += __shfl_xor(ss, off); }
    const float m = s * (1.f / 160.f);
    const float var = ss * (1.f / 160.f) - m * m;
    const float rs = rsqrtf(var + 1e-5f);
    const float g = tw[ee];
#pragma unroll
    for (int i = 0; i < 5; ++i) {
      int j = jg + 32 * i;
      float hnew = fmaxf(fmaf((v[i] - m) * rs, gu[j], beu[j]), 0.f);
      float hold = insh[nn * 324 + j];
      h[node * 160 + j] = fmaf(g, hnew - hold, hold);  // g*hnew + (1-g)*hold
    }
  }
}

// ---------------------------------------------------------------- output projection + L2 normalize
__global__ __launch_bounds__(256) void k_out(
    const float* __restrict__ h, const float* __restrict__ w_out,
    const float* __restrict__ b_out, float* __restrict__ out) {
  __shared__ float wT[160 * 132];  // wT[k*132+j] = w_out[j,k]
  __shared__ float hsh[8 * 160];
  const int t = threadIdx.x;
  for (int idx = t; idx < 128 * 160; idx += 256) {
    int j = idx / 160, k = idx - j * 160;
    wT[k * 132 + j] = w_out[idx];
  }
  const int jg = t & 31, j4 = jg * 4, slot = t >> 5;
  const float b0 = b_out[j4], b1 = b_out[j4 + 1], b2 = b_out[j4 + 2], b3 = b_out[j4 + 3];
  for (int it = 0; it < 25; ++it) {  // grid 500: 500*25*8 = 100000
    const int node0 = (blockIdx.x * 25 + it) * 8;
    __syncthreads();
    for (int q = t; q < 1280; q += 256) hsh[q] = h[node0 * 160 + q];
    __syncthreads();
    float4 acc = make_float4(b0, b1, b2, b3);
#pragma unroll 8
    for (int k = 0; k < 160; ++k) {
      float hv = hsh[slot * 160 + k];
      float4 wv = *(const float4*)&wT[k * 132 + j4];
      acc.x = fmaf(wv.x, hv, acc.x); acc.y = fmaf(wv.y, hv, acc.y);
      acc.z = fmaf(wv.z, hv, acc.z); acc.w = fmaf(wv.w, hv, acc.w);
    }
    float ss = fmaf(acc.x, acc.x, fmaf(acc.y, acc.y, fmaf(acc.z, acc.z, acc.w * acc.w)));
#pragma unroll
    for (int off = 1; off < 32; off <<= 1) ss += __shfl_xor(ss, off);
    const float inv = 1.f / fmaxf(sqrtf(ss), 1e-12f);
    float4 y = make_float4(acc.x * inv, acc.y * inv, acc.z * inv, acc.w * inv);
    *(float4*)&out[(node0 + slot) * 128 + j4] = y;
  }
}

// ---------------------------------------------------------------- launch
extern "C" void kernel_launch(void* const* d_in, const int* in_sizes, int n_in,
                              void* d_out, int out_size, void* d_ws, size_t ws_size,
                              hipStream_t stream) {
  (void)in_sizes; (void)n_in; (void)out_size; (void)ws_size;
  const float* x       = (const float*)d_in[0];
  const int*   ei      = (const int*)  d_in[1];
  const float* ew      = (const float*)d_in[2];
  const float* tsp     = (const float*)d_in[3];
  const float* w_enc   = (const float*)d_in[4];
  const float* b_enc   = (const float*)d_in[5];
  const float* g_enc   = (const float*)d_in[6];
  const float* be_enc  = (const float*)d_in[7];
  const float* w_time  = (const float*)d_in[8];
  const float* b_time  = (const float*)d_in[9];
  const float* g_time  = (const float*)d_in[10];
  const float* be_time = (const float*)d_in[11];
  const float* wm      = (const float*)d_in[12];
  const float* bm      = (const float*)d_in[13];
  const float* gm      = (const float*)d_in[14];
  const float* bem     = (const float*)d_in[15];
  const float* wu      = (const float*)d_in[16];
  const float* bu      = (const float*)d_in[17];
  const float* gu      = (const float*)d_in[18];
  const float* beu     = (const float*)d_in[19];
  const float* wg      = (const float*)d_in[20];
  const float* bg      = (const float*)d_in[21];
  const float* w_out   = (const float*)d_in[22];
  const float* b_out   = (const float*)d_in[23];
  float* out = (float*)d_out;

  float* h    = (float*)d_ws;                      // [NN,160]
  float* msum = h + (size_t)NN * 160;              // [NN,160]
  float* cnt  = msum + (size_t)NN * 160;           // [NN]

  // zero msum + cnt (contiguous): (NN*160 + NN)/4 = 4,025,000 float4
  k_zero<<<dim3((4025000 + 255) / 256), dim3(256), 0, stream>>>((float4*)msum, 4025000);
  k_encode<<<dim3(500), dim3(256), 0, stream>>>(x, tsp, w_enc, b_enc, g_enc, be_enc,
                                                w_time, b_time, g_time, be_time, h);
  k_count<<<dim3(3125), dim3(256), 0, stream>>>(ei, cnt);
  for (int l = 0; l < 2; ++l) {
    if (l) k_zero<<<dim3(15625), dim3(256), 0, stream>>>((float4*)msum, 4000000);
    k_edge<<<dim3(25000), dim3(256), 0, stream>>>(h, ei, ew,
        wm + (size_t)l * 160 * 320, bm + l * 160, gm + l * 160, bem + l * 160, msum);
    k_update<<<dim3(3125), dim3(256), 0, stream>>>(h, msum, cnt,
        wu + (size_t)l * 160 * 320, bu + l * 160, gu + l * 160, beu + l * 160,
        wg + l * 160, bg + l);
  }
  k_out<<<dim3(500), dim3(256), 0, stream>>>(h, w_out, b_out, out);
}

// Round 2
// 2893.828 us; speedup vs baseline: 2.2941x; 2.2941x over previous
//
#include <hip/hip_runtime.h>

#define NN 100000
#define NE 800000
// D = 160, 2D = 320, F = 128

__device__ __forceinline__ float bf2f(unsigned short u) {
  union { unsigned int i; float f; } c; c.i = ((unsigned int)u) << 16; return c.f;
}
__device__ __forceinline__ unsigned short f2bf(float f) {
  union { float f; unsigned int i; } c; c.f = f;
  unsigned int x = c.i;
  return (unsigned short)((x + 0x7fffu + ((x >> 16) & 1u)) >> 16);
}

// ---------------------------------------------------------------- zero
__global__ __launch_bounds__(256) void k_zero(float4* __restrict__ p, int n4) {
  int i = blockIdx.x * 256 + threadIdx.x;
  if (i < n4) p[i] = make_float4(0.f, 0.f, 0.f, 0.f);
}

// ---------------------------------------------------------------- degree count
__global__ __launch_bounds__(256) void k_count(const int* __restrict__ ei,
                                               float* __restrict__ cnt) {
  int e = blockIdx.x * 256 + threadIdx.x;  // grid exact: 3125*256 = 800000
  atomicAdd(&cnt[ei[NE + e]], 1.0f);
}

// ---------------------------------------------------------------- encoder
__global__ __launch_bounds__(256) void k_encode(
    const float* __restrict__ x, const float* __restrict__ tsp,
    const float* __restrict__ w_enc, const float* __restrict__ b_enc,
    const float* __restrict__ g_enc, const float* __restrict__ be_enc,
    const float* __restrict__ w_time, const float* __restrict__ b_time,
    const float* __restrict__ g_time, const float* __restrict__ be_time,
    float* __restrict__ h) {
  __shared__ float wT[128 * 132];  // wT[k*132+j] = w_enc[j,k]
  __shared__ float xsh[8 * 128];
  const int t = threadIdx.x;
  for (int idx = t; idx < 128 * 128; idx += 256) {
    int j = idx >> 7, k = idx & 127;
    wT[k * 132 + j] = w_enc[idx];
  }
  // time-LN closed form
  float mw = 0.f, mb = 0.f;
  for (int d = 0; d < 32; ++d) { mw += w_time[d]; mb += b_time[d]; }
  mw *= (1.f / 32.f); mb *= (1.f / 32.f);
  float A = 0.f, B = 0.f, C = 0.f;
  for (int d = 0; d < 32; ++d) {
    float a = w_time[d] - mw, c = b_time[d] - mb;
    A = fmaf(a, a, A); B = fmaf(a, c, B); C = fmaf(c, c, C);
  }
  A *= (1.f / 32.f); B *= (1.f / 32.f); C *= (1.f / 32.f);

  const int jg = t & 31, j4 = jg * 4, slot = t >> 5;
  const float be0 = b_enc[j4], be1 = b_enc[j4 + 1], be2 = b_enc[j4 + 2], be3 = b_enc[j4 + 3];
  const float g0 = g_enc[j4], g1 = g_enc[j4 + 1], g2 = g_enc[j4 + 2], g3 = g_enc[j4 + 3];
  const float s0 = be_enc[j4], s1 = be_enc[j4 + 1], s2 = be_enc[j4 + 2], s3 = be_enc[j4 + 3];
  const float wtj = w_time[jg], btj = b_time[jg], gtj = g_time[jg], stj = be_time[jg];

  for (int it = 0; it < 25; ++it) {  // grid 500
    const int node0 = (blockIdx.x * 25 + it) * 8;
    __syncthreads();
    for (int q = t; q < 1024; q += 256) xsh[q] = x[node0 * 128 + q];
    __syncthreads();
    const int node = node0 + slot;
    float4 acc = make_float4(be0, be1, be2, be3);
#pragma unroll 8
    for (int k = 0; k < 128; ++k) {
      float xv = xsh[slot * 128 + k];
      float4 wv = *(const float4*)&wT[k * 132 + j4];
      acc.x = fmaf(wv.x, xv, acc.x); acc.y = fmaf(wv.y, xv, acc.y);
      acc.z = fmaf(wv.z, xv, acc.z); acc.w = fmaf(wv.w, xv, acc.w);
    }
    float s = acc.x + acc.y + acc.z + acc.w;
    float ss = fmaf(acc.x, acc.x, fmaf(acc.y, acc.y, fmaf(acc.z, acc.z, acc.w * acc.w)));
#pragma unroll
    for (int off = 1; off < 32; off <<= 1) { s += __shfl_xor(s, off); ss += __shfl_xor(ss, off); }
    const float m = s * (1.f / 128.f);
    const float var = ss * (1.f / 128.f) - m * m;
    const float rs = rsqrtf(var + 1e-5f);
    float4 y;
    y.x = fmaxf(fmaf((acc.x - m) * rs, g0, s0), 0.f);
    y.y = fmaxf(fmaf((acc.y - m) * rs, g1, s1), 0.f);
    y.z = fmaxf(fmaf((acc.z - m) * rs, g2, s2), 0.f);
    y.w = fmaxf(fmaf((acc.w - m) * rs, g3, s3), 0.f);
    *(float4*)&h[node * 160 + j4] = y;
    const float tsv = tsp[node];
    const float mt = fmaf(mw, tsv, mb);
    const float vart = fmaf(fmaf(A, tsv, 2.f * B), tsv, C);
    const float rst = rsqrtf(vart + 1e-5f);
    const float v = fmaf(wtj, tsv, btj);
    h[node * 160 + 128 + jg] = fmaxf(fmaf((v - mt) * rst, gtj, stj), 0.f);
  }
}

// ---------------------------------------------------------------- per-node projection
// P[n, j]      = sum_k h[n,k] * wm[j, k]          (j in 0..159)
// P[n, 160+j]  = sum_k h[n,k] * wm[j, 160+k] + bm[j]
// stored bf16. block 256 = 8 groups x 32 lanes; group -> 4 nodes; lane -> 10 outs.
__global__ __launch_bounds__(256) void k_proj(
    const float* __restrict__ h, const float* __restrict__ wm, const float* __restrict__ bm,
    unsigned short* __restrict__ P) {
  __shared__ float insh[32 * 164];
  __shared__ float wsh[320 * 36];
  const int t = threadIdx.x;
  const int n0 = blockIdx.x * 32;  // grid exact: 3125*32 = 100000
#pragma unroll
  for (int r = 0; r < 5; ++r) {
    int q = t + r * 256;  // 1280 float4 = 32 rows * 40
    int nn = q / 40, o = q - nn * 40;
    *(float4*)&insh[nn * 164 + o * 4] = *(const float4*)&h[(n0 + nn) * 160 + o * 4];
  }
  const int jg = t & 31, eg = t >> 5;
  float acc[4][10];
#pragma unroll
  for (int a = 0; a < 4; ++a)
#pragma unroll
    for (int b = 0; b < 10; ++b) acc[a][b] = 0.f;

  for (int kt = 0; kt < 5; ++kt) {  // K = 160 in tiles of 32
    __syncthreads();
#pragma unroll
    for (int r = 0; r < 40; ++r) {
      int q = t + r * 256;  // 10240 = 320*32
      int j2 = q >> 5, kk = q & 31;
      wsh[j2 * 36 + kk] = (j2 < 160) ? wm[j2 * 320 + kt * 32 + kk]
                                     : wm[(j2 - 160) * 320 + 160 + kt * 32 + kk];
    }
    __syncthreads();
    const int kbase = kt * 32;
#pragma unroll
    for (int kq = 0; kq < 8; ++kq) {
      const int kl = kq * 4;
      float4 a[4];
#pragma unroll
      for (int ee = 0; ee < 4; ++ee)
        a[ee] = *(const float4*)&insh[(eg * 4 + ee) * 164 + kbase + kl];
#pragma unroll
      for (int i = 0; i < 10; ++i) {
        float4 b = *(const float4*)&wsh[(jg + 32 * i) * 36 + kl];
#pragma unroll
        for (int ee = 0; ee < 4; ++ee)
          acc[ee][i] = fmaf(a[ee].x, b.x, fmaf(a[ee].y, b.y, fmaf(a[ee].z, b.z, fmaf(a[ee].w, b.w, acc[ee][i]))));
      }
    }
  }
#pragma unroll
  for (int ee = 0; ee < 4; ++ee) {
    const int node = n0 + eg * 4 + ee;
#pragma unroll
    for (int i = 0; i < 10; ++i) {
      int j2 = jg + 32 * i;
      float v = acc[ee][i] + ((j2 >= 160) ? bm[j2 - 160] : 0.f);
      P[(size_t)node * 320 + j2] = f2bf(v);
    }
  }
}

// ---------------------------------------------------------------- edge: gather + LN + scatter
// half-wave (32 lanes) per edge, lane jg handles dims jg+32i (i<5)
__global__ __launch_bounds__(256) void k_edge2(
    const unsigned short* __restrict__ P, const int* __restrict__ ei,
    const float* __restrict__ ew,
    const float* __restrict__ gm, const float* __restrict__ bem,
    float* __restrict__ msum) {
  const int t = threadIdx.x;
  const int jg = t & 31, g = t >> 5;
  float gmv[5], bev[5];
#pragma unroll
  for (int i = 0; i < 5; ++i) { gmv[i] = gm[jg + 32 * i]; bev[i] = bem[jg + 32 * i]; }
  int e = blockIdx.x * 64 + g;  // grid exact: 12500*64 = 800000
#pragma unroll 2
  for (int it = 0; it < 8; ++it, e += 8) {
    const int src = ei[e], dst = ei[NE + e];
    const float we = ew[e];
    const unsigned short* ps = P + (size_t)src * 320;
    const unsigned short* pd = P + (size_t)dst * 320 + 160;
    float v[5], s = 0.f, ss = 0.f;
#pragma unroll
    for (int i = 0; i < 5; ++i) {
      v[i] = bf2f(ps[jg + 32 * i]) + bf2f(pd[jg + 32 * i]);
      s += v[i]; ss = fmaf(v[i], v[i], ss);
    }
#pragma unroll
    for (int off = 1; off < 32; off <<= 1) { s += __shfl_xor(s, off); ss += __shfl_xor(ss, off); }
    const float m = s * (1.f / 160.f);
    const float var = ss * (1.f / 160.f) - m * m;
    const float rs = rsqrtf(var + 1e-5f);
    float* mrow = &msum[(size_t)dst * 160];
#pragma unroll
    for (int i = 0; i < 5; ++i) {
      float y = fmaxf(fmaf((v[i] - m) * rs, gmv[i], bev[i]), 0.f) * we;
      atomicAdd(&mrow[jg + 32 * i], y);
    }
  }
}

// ---------------------------------------------------------------- node update MLP + gate
__global__ __launch_bounds__(256) void k_update(
    float* __restrict__ h, const float* __restrict__ msum, const float* __restrict__ cnt,
    const float* __restrict__ wu, const float* __restrict__ bu,
    const float* __restrict__ gu, const float* __restrict__ beu,
    const float* __restrict__ wg, const float* __restrict__ bg) {
  __shared__ float insh[32 * 324];
  __shared__ float wsh[160 * 36];
  const int t = threadIdx.x;
  const int n0 = blockIdx.x * 32;  // grid exact: 3125*32 = 100000
#pragma unroll
  for (int r = 0; r < 10; ++r) {
    int q = t + r * 256;
    int nn = q / 80, o = q % 80;
    int node = n0 + nn;
    float4 v;
    if (o < 40) {
      v = *(const float4*)&h[node * 160 + o * 4];
    } else {
      float c = cnt[node];
      float ic = (c > 0.f) ? 1.f / (c + 1e-8f) : 0.f;
      v = *(const float4*)&msum[node * 160 + (o - 40) * 4];
      v.x *= ic; v.y *= ic; v.z *= ic; v.w *= ic;
    }
    *(float4*)&insh[nn * 324 + o * 4] = v;
  }
  __syncthreads();
  const int jg = t & 31, eg = t >> 5;
  const float bgv = bg[0];
  float tw[4];
#pragma unroll
  for (int ee = 0; ee < 4; ++ee) {
    const int nn = eg * 4 + ee;
    float gp = 0.f;
#pragma unroll
    for (int i = 0; i < 5; ++i) {
      int j = jg + 32 * i;
      gp = fmaf(wg[j], insh[nn * 324 + j], gp);
    }
#pragma unroll
    for (int off = 1; off < 32; off <<= 1) gp += __shfl_xor(gp, off);
    tw[ee] = 1.f / (1.f + expf(-(gp + bgv)));
  }
  float acc[4][5];
#pragma unroll
  for (int a = 0; a < 4; ++a)
#pragma unroll
    for (int b = 0; b < 5; ++b) acc[a][b] = 0.f;

  for (int kt = 0; kt < 10; ++kt) {
    __syncthreads();
#pragma unroll
    for (int r = 0; r < 20; ++r) {
      int q = t + r * 256;
      int j = q >> 5, kk = q & 31;
      wsh[j * 36 + kk] = wu[j * 320 + kt * 32 + kk];
    }
    __syncthreads();
    const int kbase = kt * 32;
#pragma unroll
    for (int kq = 0; kq < 8; ++kq) {
      const int kl = kq * 4;
      float4 b[5];
#pragma unroll
      for (int i = 0; i < 5; ++i) b[i] = *(const float4*)&wsh[(jg + 32 * i) * 36 + kl];
#pragma unroll
      for (int ee = 0; ee < 4; ++ee) {
        float4 a = *(const float4*)&insh[(eg * 4 + ee) * 324 + kbase + kl];
#pragma unroll
        for (int i = 0; i < 5; ++i)
          acc[ee][i] = fmaf(a.x, b[i].x, fmaf(a.y, b[i].y, fmaf(a.z, b[i].z, fmaf(a.w, b[i].w, acc[ee][i]))));
      }
    }
  }
#pragma unroll
  for (int ee = 0; ee < 4; ++ee) {
    const int nn = eg * 4 + ee;
    const int node = n0 + nn;
    float v[5], s = 0.f, ss = 0.f;
#pragma unroll
    for (int i = 0; i < 5; ++i) {
      v[i] = acc[ee][i] + bu[jg + 32 * i];
      s += v[i]; ss = fmaf(v[i], v[i], ss);
    }
#pragma unroll
    for (int off = 1; off < 32; off <<= 1) { s += __shfl_xor(s, off); ss += __shfl_xor(ss, off); }
    const float m = s * (1.f / 160.f);
    const float var = ss * (1.f / 160.f) - m * m;
    const float rs = rsqrtf(var + 1e-5f);
    const float g = tw[ee];
#pragma unroll
    for (int i = 0; i < 5; ++i) {
      int j = jg + 32 * i;
      float hnew = fmaxf(fmaf((v[i] - m) * rs, gu[j], beu[j]), 0.f);
      float hold = insh[nn * 324 + j];
      h[node * 160 + j] = fmaf(g, hnew - hold, hold);
    }
  }
}

// ---------------------------------------------------------------- output projection + L2 normalize
__global__ __launch_bounds__(256) void k_out(
    const float* __restrict__ h, const float* __restrict__ w_out,
    const float* __restrict__ b_out, float* __restrict__ out) {
  __shared__ float wT[160 * 132];
  __shared__ float hsh[8 * 160];
  const int t = threadIdx.x;
  for (int idx = t; idx < 128 * 160; idx += 256) {
    int j = idx / 160, k = idx - j * 160;
    wT[k * 132 + j] = w_out[idx];
  }
  const int jg = t & 31, j4 = jg * 4, slot = t >> 5;
  const float b0 = b_out[j4], b1 = b_out[j4 + 1], b2 = b_out[j4 + 2], b3 = b_out[j4 + 3];
  for (int it = 0; it < 25; ++it) {  // grid 500
    const int node0 = (blockIdx.x * 25 + it) * 8;
    __syncthreads();
    for (int q = t; q < 1280; q += 256) hsh[q] = h[node0 * 160 + q];
    __syncthreads();
    float4 acc = make_float4(b0, b1, b2, b3);
#pragma unroll 8
    for (int k = 0; k < 160; ++k) {
      float hv = hsh[slot * 160 + k];
      float4 wv = *(const float4*)&wT[k * 132 + j4];
      acc.x = fmaf(wv.x, hv, acc.x); acc.y = fmaf(wv.y, hv, acc.y);
      acc.z = fmaf(wv.z, hv, acc.z); acc.w = fmaf(wv.w, hv, acc.w);
    }
    float ss = fmaf(acc.x, acc.x, fmaf(acc.y, acc.y, fmaf(acc.z, acc.z, acc.w * acc.w)));
#pragma unroll
    for (int off = 1; off < 32; off <<= 1) ss += __shfl_xor(ss, off);
    const float inv = 1.f / fmaxf(sqrtf(ss), 1e-12f);
    float4 y = make_float4(acc.x * inv, acc.y * inv, acc.z * inv, acc.w * inv);
    *(float4*)&out[(node0 + slot) * 128 + j4] = y;
  }
}

// ---------------------------------------------------------------- launch
extern "C" void kernel_launch(void* const* d_in, const int* in_sizes, int n_in,
                              void* d_out, int out_size, void* d_ws, size_t ws_size,
                              hipStream_t stream) {
  (void)in_sizes; (void)n_in; (void)out_size; (void)ws_size;
  const float* x       = (const float*)d_in[0];
  const int*   ei      = (const int*)  d_in[1];
  const float* ew      = (const float*)d_in[2];
  const float* tsp     = (const float*)d_in[3];
  const float* w_enc   = (const float*)d_in[4];
  const float* b_enc   = (const float*)d_in[5];
  const float* g_enc   = (const float*)d_in[6];
  const float* be_enc  = (const float*)d_in[7];
  const float* w_time  = (const float*)d_in[8];
  const float* b_time  = (const float*)d_in[9];
  const float* g_time  = (const float*)d_in[10];
  const float* be_time = (const float*)d_in[11];
  const float* wm      = (const float*)d_in[12];
  const float* bm      = (const float*)d_in[13];
  const float* gm      = (const float*)d_in[14];
  const float* bem     = (const float*)d_in[15];
  const float* wu      = (const float*)d_in[16];
  const float* bu      = (const float*)d_in[17];
  const float* gu      = (const float*)d_in[18];
  const float* beu     = (const float*)d_in[19];
  const float* wg      = (const float*)d_in[20];
  const float* bg      = (const float*)d_in[21];
  const float* w_out   = (const float*)d_in[22];
  const float* b_out   = (const float*)d_in[23];
  float* out = (float*)d_out;

  // workspace layout (bytes):
  //   h    : [NN*160] f32  @ 0           (64.0 MB)
  //   msum : [NN*160] f32  @ 64,000,000  (64.0 MB)
  //   cnt  : [NN]     f32  @ 128,000,000 (0.4 MB)
  //   P    : [NN*320] bf16 @ 128,400,128 (64.0 MB)   total ~192.4 MB
  char* ws = (char*)d_ws;
  float* h    = (float*)ws;
  float* msum = (float*)(ws + 64000000);
  float* cnt  = (float*)(ws + 128000000);
  unsigned short* P = (unsigned short*)(ws + 128400128);

  // zero msum + cnt (contiguous): (NN*160 + NN)/4 = 4,025,000 float4
  k_zero<<<dim3((4025000 + 255) / 256), dim3(256), 0, stream>>>((float4*)msum, 4025000);
  k_encode<<<dim3(500), dim3(256), 0, stream>>>(x, tsp, w_enc, b_enc, g_enc, be_enc,
                                                w_time, b_time, g_time, be_time, h);
  k_count<<<dim3(3125), dim3(256), 0, stream>>>(ei, cnt);
  for (int l = 0; l < 2; ++l) {
    if (l) k_zero<<<dim3(15625), dim3(256), 0, stream>>>((float4*)msum, 4000000);
    k_proj<<<dim3(3125), dim3(256), 0, stream>>>(h, wm + (size_t)l * 160 * 320, bm + l * 160, P);
    k_edge2<<<dim3(12500), dim3(256), 0, stream>>>(P, ei, ew, gm + l * 160, bem + l * 160, msum);
    k_update<<<dim3(3125), dim3(256), 0, stream>>>(h, msum, cnt,
        wu + (size_t)l * 160 * 320, bu + l * 160, gu + l * 160, beu + l * 160,
        wg + l * 160, bg + l);
  }
  k_out<<<dim3(500), dim3(256), 0, stream>>>(h, w_out, b_out, out);
}

// Round 3
// 1518.447 us; speedup vs baseline: 4.3721x; 1.9058x over previous
//
#include <hip/hip_runtime.h>

#define NN 100000
#define NE 800000
// D = 160, 2D = 320, F = 128

typedef _Float16 half8 __attribute__((ext_vector_type(8)));
typedef _Float16 half4 __attribute__((ext_vector_type(4)));
typedef float floatx4 __attribute__((ext_vector_type(4)));

// ---------------------------------------------------------------- zero
__global__ __launch_bounds__(256) void k_zero(float4* __restrict__ p, int n4) {
  int i = blockIdx.x * 256 + threadIdx.x;
  if (i < n4) p[i] = make_float4(0.f, 0.f, 0.f, 0.f);
}

// ---------------------------------------------------------------- degree count
__global__ __launch_bounds__(256) void k_count(const int* __restrict__ ei,
                                               float* __restrict__ cnt) {
  int e = blockIdx.x * 256 + threadIdx.x;  // grid exact: 3125*256 = 800000
  atomicAdd(&cnt[ei[NE + e]], 1.0f);
}

// ---------------------------------------------------------------- weight casts
__global__ __launch_bounds__(256) void k_cast(const float* __restrict__ s,
                                              _Float16* __restrict__ d, int n) {
  int i = blockIdx.x * 256 + threadIdx.x;
  if (i < n) d[i] = (_Float16)s[i];
}
// Wp[l][j2][k] (j2<160: wm[l][j2][k], else wm[l][j2-160][160+k]); total 2*320*160
__global__ __launch_bounds__(256) void k_prep_wm(const float* __restrict__ wm,
                                                 _Float16* __restrict__ Wp) {
  int i = blockIdx.x * 256 + threadIdx.x;
  if (i >= 102400) return;
  int l = i / 51200, rem = i - l * 51200;
  int j2 = rem / 160, k = rem - j2 * 160;
  float v = (j2 < 160) ? wm[l * 51200 + j2 * 320 + k]
                       : wm[l * 51200 + (j2 - 160) * 320 + 160 + k];
  Wp[i] = (_Float16)v;
}

// ---------------------------------------------------------------- encoder (MFMA)
// h[n,0:128] = relu(LN(x @ We^T + b_enc)); h[n,128:160] = time-LN closed form
__global__ __launch_bounds__(256) void k_encode(
    const float* __restrict__ x, const float* __restrict__ tsp,
    const _Float16* __restrict__ We,
    const float* __restrict__ b_enc, const float* __restrict__ g_enc,
    const float* __restrict__ be_enc,
    const float* __restrict__ w_time, const float* __restrict__ b_time,
    const float* __restrict__ g_time, const float* __restrict__ be_time,
    float* __restrict__ h) {
  __shared__ _Float16 Ash[64 * 136];  // stride 272 B (68 dw, %32 = 4)
  const int t = threadIdx.x;
  const int n0 = blockIdx.x * 64;  // grid 1563, tail 32
#pragma unroll
  for (int r = 0; r < 8; ++r) {
    int q = t + r * 256;  // 2048 float4 = 64 rows x 32
    int nn = q >> 5, o = q & 31;
    int node = n0 + nn; if (node > NN - 1) node = NN - 1;
    float4 v = *(const float4*)&x[(size_t)node * 128 + o * 4];
    half4 hv = {(_Float16)v.x, (_Float16)v.y, (_Float16)v.z, (_Float16)v.w};
    *(half4*)&Ash[nn * 136 + o * 4] = hv;
  }
  __syncthreads();
  const int lane = t & 63, w = t >> 6;
  const int mrow = lane & 15, quad = lane >> 4;
  const int arow = w * 16 + mrow;
  floatx4 acc[8];
#pragma unroll
  for (int i = 0; i < 8; ++i) acc[i] = (floatx4)0.f;
  const _Float16* wbase = We + (size_t)mrow * 128 + quad * 8;
  for (int kt = 0; kt < 4; ++kt) {
    half8 a = *(const half8*)&Ash[arow * 136 + kt * 32 + quad * 8];
#pragma unroll
    for (int i = 0; i < 8; ++i) {
      half8 b = *(const half8*)&wbase[i * 16 * 128 + kt * 32];
      acc[i] = __builtin_amdgcn_mfma_f32_16x16x32_f16(a, b, acc[i], 0, 0, 0);
    }
  }
#pragma unroll
  for (int r = 0; r < 4; ++r) {
    const int row = quad * 4 + r;
    const int node = n0 + w * 16 + row;
    float v[8], s = 0.f, ss = 0.f;
#pragma unroll
    for (int i = 0; i < 8; ++i) {
      v[i] = acc[i][r] + b_enc[i * 16 + mrow];
      s += v[i]; ss = fmaf(v[i], v[i], ss);
    }
#pragma unroll
    for (int off = 1; off < 16; off <<= 1) { s += __shfl_xor(s, off); ss += __shfl_xor(ss, off); }
    const float m = s * (1.f / 128.f);
    const float var = ss * (1.f / 128.f) - m * m;
    const float rs = rsqrtf(var + 1e-5f);
    if (node < NN) {
#pragma unroll
      for (int i = 0; i < 8; ++i) {
        int j = i * 16 + mrow;
        h[(size_t)node * 160 + j] = fmaxf(fmaf((v[i] - m) * rs, g_enc[j], be_enc[j]), 0.f);
      }
    }
  }
  // time dims 128..159, closed form LN
  float mw = 0.f, mb = 0.f;
  for (int d = 0; d < 32; ++d) { mw += w_time[d]; mb += b_time[d]; }
  mw *= (1.f / 32.f); mb *= (1.f / 32.f);
  float A = 0.f, B = 0.f, C = 0.f;
  for (int d = 0; d < 32; ++d) {
    float a = w_time[d] - mw, c = b_time[d] - mb;
    A = fmaf(a, a, A); B = fmaf(a, c, B); C = fmaf(c, c, C);
  }
  A *= (1.f / 32.f); B *= (1.f / 32.f); C *= (1.f / 32.f);
#pragma unroll
  for (int r2 = 0; r2 < 8; ++r2) {
    int q = t + r2 * 256;  // 2048 = 64 nodes x 32 dims
    int nn = q >> 5, d = q & 31;
    int node = n0 + nn;
    if (node < NN) {
      float tsv = tsp[node];
      float mt = fmaf(mw, tsv, mb);
      float vart = fmaf(fmaf(A, tsv, 2.f * B), tsv, C);
      float rst = rsqrtf(vart + 1e-5f);
      float vv = fmaf(w_time[d], tsv, b_time[d]);
      h[(size_t)node * 160 + 128 + d] = fmaxf(fmaf((vv - mt) * rst, g_time[d], be_time[d]), 0.f);
    }
  }
}

// ---------------------------------------------------------------- per-node projection (MFMA)
// P[n, 0:320] f16 = h[n,:] @ Wp^T (+ bm on cols >=160)
__global__ __launch_bounds__(256) void k_proj(
    const float* __restrict__ h, const _Float16* __restrict__ Wp,
    const float* __restrict__ bm, _Float16* __restrict__ P) {
  __shared__ _Float16 Ash[64 * 168];  // stride 336 B (84 dw, %32 = 20)
  const int t = threadIdx.x;
  const int n0 = blockIdx.x * 64;  // grid 1563
#pragma unroll
  for (int r = 0; r < 10; ++r) {
    int q = t + r * 256;  // 2560 float4 = 64 rows x 40
    int nn = q / 40, o = q - nn * 40;
    int node = n0 + nn; if (node > NN - 1) node = NN - 1;
    float4 v = *(const float4*)&h[(size_t)node * 160 + o * 4];
    half4 hv = {(_Float16)v.x, (_Float16)v.y, (_Float16)v.z, (_Float16)v.w};
    *(half4*)&Ash[nn * 168 + o * 4] = hv;
  }
  __syncthreads();
  const int lane = t & 63, w = t >> 6;
  const int mrow = lane & 15, quad = lane >> 4;
  const int arow = w * 16 + mrow;
  floatx4 acc[20];
#pragma unroll
  for (int i = 0; i < 20; ++i) acc[i] = (floatx4)0.f;
  const _Float16* wbase = Wp + (size_t)mrow * 160 + quad * 8;
  for (int kt = 0; kt < 5; ++kt) {
    half8 a = *(const half8*)&Ash[arow * 168 + kt * 32 + quad * 8];
#pragma unroll
    for (int i = 0; i < 20; ++i) {
      half8 b = *(const half8*)&wbase[i * 16 * 160 + kt * 32];
      acc[i] = __builtin_amdgcn_mfma_f32_16x16x32_f16(a, b, acc[i], 0, 0, 0);
    }
  }
#pragma unroll
  for (int r = 0; r < 4; ++r) {
    const int row = quad * 4 + r;
    const int node = n0 + w * 16 + row;
    if (node < NN) {
      _Float16* prow = &P[(size_t)node * 320];
#pragma unroll
      for (int i = 0; i < 20; ++i) {
        int j2 = i * 16 + mrow;
        float v2 = acc[i][r] + ((j2 >= 160) ? bm[j2 - 160] : 0.f);
        prow[j2] = (_Float16)v2;
      }
    }
  }
}

// ---------------------------------------------------------------- edge: gather + LN + scatter
__global__ __launch_bounds__(256) void k_edge2(
    const _Float16* __restrict__ P, const int* __restrict__ ei,
    const float* __restrict__ ew,
    const float* __restrict__ gm, const float* __restrict__ bem,
    float* __restrict__ msum) {
  const int t = threadIdx.x;
  const int jg = t & 31, g = t >> 5;
  float gmv[5], bev[5];
#pragma unroll
  for (int i = 0; i < 5; ++i) { gmv[i] = gm[jg + 32 * i]; bev[i] = bem[jg + 32 * i]; }
  int e = blockIdx.x * 64 + g;  // grid exact: 12500*64 = 800000
#pragma unroll 2
  for (int it = 0; it < 8; ++it, e += 8) {
    const int src = ei[e], dst = ei[NE + e];
    const float we = ew[e];
    const _Float16* ps = P + (size_t)src * 320;
    const _Float16* pd = P + (size_t)dst * 320 + 160;
    float v[5], s = 0.f, ss = 0.f;
#pragma unroll
    for (int i = 0; i < 5; ++i) {
      v[i] = (float)ps[jg + 32 * i] + (float)pd[jg + 32 * i];
      s += v[i]; ss = fmaf(v[i], v[i], ss);
    }
#pragma unroll
    for (int off = 1; off < 32; off <<= 1) { s += __shfl_xor(s, off); ss += __shfl_xor(ss, off); }
    const float m = s * (1.f / 160.f);
    const float var = ss * (1.f / 160.f) - m * m;
    const float rs = rsqrtf(var + 1e-5f);
    float* mrow = &msum[(size_t)dst * 160];
#pragma unroll
    for (int i = 0; i < 5; ++i) {
      float y = fmaxf(fmaf((v[i] - m) * rs, gmv[i], bev[i]), 0.f) * we;
      atomicAdd(&mrow[jg + 32 * i], y);
    }
  }
}

// ---------------------------------------------------------------- node update (MFMA) + gate
__global__ __launch_bounds__(256) void k_update(
    float* __restrict__ h, const float* __restrict__ msum, const float* __restrict__ cnt,
    const _Float16* __restrict__ Wu, const float* __restrict__ bu,
    const float* __restrict__ gu, const float* __restrict__ beu,
    const float* __restrict__ wg, const float* __restrict__ bg) {
  __shared__ _Float16 Ash[64 * 328];  // stride 656 B (164 dw, %32 = 4)
  const int t = threadIdx.x;
  const int n0 = blockIdx.x * 64;  // grid 1563
#pragma unroll
  for (int r = 0; r < 20; ++r) {
    int q = t + r * 256;  // 5120 float4 = 64 rows x 80
    int nn = q / 80, o = q - nn * 80;
    int node = n0 + nn; if (node > NN - 1) node = NN - 1;
    float4 v;
    if (o < 40) {
      v = *(const float4*)&h[(size_t)node * 160 + o * 4];
    } else {
      float c = cnt[node];
      float ic = (c > 0.f) ? 1.f / (c + 1e-8f) : 0.f;
      v = *(const float4*)&msum[(size_t)node * 160 + (o - 40) * 4];
      v.x *= ic; v.y *= ic; v.z *= ic; v.w *= ic;
    }
    half4 hv = {(_Float16)v.x, (_Float16)v.y, (_Float16)v.z, (_Float16)v.w};
    *(half4*)&Ash[nn * 328 + o * 4] = hv;
  }
  __syncthreads();
  const int lane = t & 63, w = t >> 6;
  const int mrow = lane & 15, quad = lane >> 4;
  const int arow = w * 16 + mrow;
  // gate: dot(wg, h-part) per node; lane covers dims quad*40..+40 for node (w*16+mrow)
  float gp = 0.f;
#pragma unroll
  for (int d = 0; d < 40; ++d)
    gp = fmaf(wg[quad * 40 + d], (float)Ash[arow * 328 + quad * 40 + d], gp);
  gp += __shfl_xor(gp, 16); gp += __shfl_xor(gp, 32);
  const float twv = 1.f / (1.f + expf(-(gp + bg[0])));
  // GEMM: 16 rows x 160 cols, K=320
  floatx4 acc[10];
#pragma unroll
  for (int i = 0; i < 10; ++i) acc[i] = (floatx4)0.f;
  const _Float16* wbase = Wu + (size_t)mrow * 320 + quad * 8;
  for (int kt = 0; kt < 10; ++kt) {
    half8 a = *(const half8*)&Ash[arow * 328 + kt * 32 + quad * 8];
#pragma unroll
    for (int i = 0; i < 10; ++i) {
      half8 b = *(const half8*)&wbase[i * 16 * 320 + kt * 32];
      acc[i] = __builtin_amdgcn_mfma_f32_16x16x32_f16(a, b, acc[i], 0, 0, 0);
    }
  }
#pragma unroll
  for (int r = 0; r < 4; ++r) {
    const int row = quad * 4 + r;
    const int node = n0 + w * 16 + row;
    float v[10], s = 0.f, ss = 0.f;
#pragma unroll
    for (int i = 0; i < 10; ++i) {
      v[i] = acc[i][r] + bu[i * 16 + mrow];
      s += v[i]; ss = fmaf(v[i], v[i], ss);
    }
#pragma unroll
    for (int off = 1; off < 16; off <<= 1) { s += __shfl_xor(s, off); ss += __shfl_xor(ss, off); }
    const float m = s * (1.f / 160.f);
    const float var = ss * (1.f / 160.f) - m * m;
    const float rs = rsqrtf(var + 1e-5f);
    const float g = __shfl(twv, row);  // tw for node n0+w*16+row (lane "row" of this wave)
    if (node < NN) {
      float* hrow = &h[(size_t)node * 160];
#pragma unroll
      for (int i = 0; i < 10; ++i) {
        int j = i * 16 + mrow;
        float hnew = fmaxf(fmaf((v[i] - m) * rs, gu[j], beu[j]), 0.f);
        float hold = hrow[j];  // exact f32 old h (L1-hot, staged above)
        hrow[j] = fmaf(g, hnew - hold, hold);
      }
    }
  }
}

// ---------------------------------------------------------------- output projection (MFMA) + L2 norm
__global__ __launch_bounds__(256) void k_out(
    const float* __restrict__ h, const _Float16* __restrict__ Wo,
    const float* __restrict__ b_out, float* __restrict__ out) {
  __shared__ _Float16 Ash[64 * 168];
  const int t = threadIdx.x;
  const int n0 = blockIdx.x * 64;  // grid 1563
#pragma unroll
  for (int r = 0; r < 10; ++r) {
    int q = t + r * 256;
    int nn = q / 40, o = q - nn * 40;
    int node = n0 + nn; if (node > NN - 1) node = NN - 1;
    float4 v = *(const float4*)&h[(size_t)node * 160 + o * 4];
    half4 hv = {(_Float16)v.x, (_Float16)v.y, (_Float16)v.z, (_Float16)v.w};
    *(half4*)&Ash[nn * 168 + o * 4] = hv;
  }
  __syncthreads();
  const int lane = t & 63, w = t >> 6;
  const int mrow = lane & 15, quad = lane >> 4;
  const int arow = w * 16 + mrow;
  floatx4 acc[8];
#pragma unroll
  for (int i = 0; i < 8; ++i) acc[i] = (floatx4)0.f;
  const _Float16* wbase = Wo + (size_t)mrow * 160 + quad * 8;
  for (int kt = 0; kt < 5; ++kt) {
    half8 a = *(const half8*)&Ash[arow * 168 + kt * 32 + quad * 8];
#pragma unroll
    for (int i = 0; i < 8; ++i) {
      half8 b = *(const half8*)&wbase[i * 16 * 160 + kt * 32];
      acc[i] = __builtin_amdgcn_mfma_f32_16x16x32_f16(a, b, acc[i], 0, 0, 0);
    }
  }
#pragma unroll
  for (int r = 0; r < 4; ++r) {
    const int row = quad * 4 + r;
    const int node = n0 + w * 16 + row;
    float v[8], ss = 0.f;
#pragma unroll
    for (int i = 0; i < 8; ++i) {
      v[i] = acc[i][r] + b_out[i * 16 + mrow];
      ss = fmaf(v[i], v[i], ss);
    }
#pragma unroll
    for (int off = 1; off < 16; off <<= 1) ss += __shfl_xor(ss, off);
    const float inv = 1.f / fmaxf(sqrtf(ss), 1e-12f);
    if (node < NN) {
#pragma unroll
      for (int i = 0; i < 8; ++i)
        out[(size_t)node * 128 + i * 16 + mrow] = v[i] * inv;
    }
  }
}

// ---------------------------------------------------------------- launch
extern "C" void kernel_launch(void* const* d_in, const int* in_sizes, int n_in,
                              void* d_out, int out_size, void* d_ws, size_t ws_size,
                              hipStream_t stream) {
  (void)in_sizes; (void)n_in; (void)out_size; (void)ws_size;
  const float* x       = (const float*)d_in[0];
  const int*   ei      = (const int*)  d_in[1];
  const float* ew      = (const float*)d_in[2];
  const float* tsp     = (const float*)d_in[3];
  const float* w_enc   = (const float*)d_in[4];
  const float* b_enc   = (const float*)d_in[5];
  const float* g_enc   = (const float*)d_in[6];
  const float* be_enc  = (const float*)d_in[7];
  const float* w_time  = (const float*)d_in[8];
  const float* b_time  = (const float*)d_in[9];
  const float* g_time  = (const float*)d_in[10];
  const float* be_time = (const float*)d_in[11];
  const float* wm      = (const float*)d_in[12];
  const float* bm      = (const float*)d_in[13];
  const float* gm      = (const float*)d_in[14];
  const float* bem     = (const float*)d_in[15];
  const float* wu      = (const float*)d_in[16];
  const float* bu      = (const float*)d_in[17];
  const float* gu      = (const float*)d_in[18];
  const float* beu     = (const float*)d_in[19];
  const float* wg      = (const float*)d_in[20];
  const float* bg      = (const float*)d_in[21];
  const float* w_out   = (const float*)d_in[22];
  const float* b_out   = (const float*)d_in[23];
  float* out = (float*)d_out;

  // ws layout (bytes):
  //   h    f32[NN*160] @ 0            (64,000,000)
  //   msum f32[NN*160] @ 64,000,000   (64,000,000)
  //   cnt  f32[NN]     @ 128,000,000  (400,000)
  //   Wo16 f16[128*160]@ 128,400,000  (40,960)
  //   P    f16[NN*320] @ 128,440,960  (64,000,000)  -> total 192,440,960
  char* ws = (char*)d_ws;
  float* h    = (float*)ws;
  float* msum = (float*)(ws + 64000000);
  float* cnt  = (float*)(ws + 128000000);
  _Float16* Wo16 = (_Float16*)(ws + 128400000);
  _Float16* P    = (_Float16*)(ws + 128440960);
  // big f16 weight copies live in d_out (scratch until k_out overwrites it):
  //   Wp16 2*320*160 @ 0, Wu16 2*160*320 @ 204,800 B, We16 128*128 @ 409,600 B
  char* ob = (char*)d_out;
  _Float16* Wp16 = (_Float16*)ob;
  _Float16* Wu16 = (_Float16*)(ob + 204800);
  _Float16* We16 = (_Float16*)(ob + 409600);

  // zero msum + cnt: 4,025,000 float4 = 64,400,000 B (ends exactly at Wo16)
  k_zero<<<dim3((4025000 + 255) / 256), dim3(256), 0, stream>>>((float4*)msum, 4025000);
  // weight prep
  k_cast<<<dim3(400), dim3(256), 0, stream>>>(wu, Wu16, 102400);
  k_cast<<<dim3(64),  dim3(256), 0, stream>>>(w_enc, We16, 16384);
  k_cast<<<dim3(80),  dim3(256), 0, stream>>>(w_out, Wo16, 20480);
  k_prep_wm<<<dim3(400), dim3(256), 0, stream>>>(wm, Wp16);

  k_encode<<<dim3(1563), dim3(256), 0, stream>>>(x, tsp, We16, b_enc, g_enc, be_enc,
                                                 w_time, b_time, g_time, be_time, h);
  k_count<<<dim3(3125), dim3(256), 0, stream>>>(ei, cnt);
  for (int l = 0; l < 2; ++l) {
    if (l) k_zero<<<dim3(15625), dim3(256), 0, stream>>>((float4*)msum, 4000000);
    k_proj<<<dim3(1563), dim3(256), 0, stream>>>(h, Wp16 + (size_t)l * 51200, bm + l * 160, P);
    k_edge2<<<dim3(12500), dim3(256), 0, stream>>>(P, ei, ew, gm + l * 160, bem + l * 160, msum);
    k_update<<<dim3(1563), dim3(256), 0, stream>>>(h, msum, cnt,
        Wu16 + (size_t)l * 51200, bu + l * 160, gu + l * 160, beu + l * 160,
        wg + l * 160, bg + l);
  }
  k_out<<<dim3(1563), dim3(256), 0, stream>>>(h, Wo16, b_out, out);
}

// Round 4
// 865.947 us; speedup vs baseline: 7.6666x; 1.7535x over previous
//
#include <hip/hip_runtime.h>

#define NN 100000
#define NE 800000
// D = 160, 2D = 320, F = 128

typedef _Float16 half8 __attribute__((ext_vector_type(8)));
typedef _Float16 half4 __attribute__((ext_vector_type(4)));
typedef float floatx4 __attribute__((ext_vector_type(4)));

// ---------------------------------------------------------------- zero
__global__ __launch_bounds__(256) void k_zero(float4* __restrict__ p, int n4) {
  int i = blockIdx.x * 256 + threadIdx.x;
  if (i < n4) p[i] = make_float4(0.f, 0.f, 0.f, 0.f);
}

// ---------------------------------------------------------------- weight casts
__global__ __launch_bounds__(256) void k_cast(const float* __restrict__ s,
                                              _Float16* __restrict__ d, int n) {
  int i = blockIdx.x * 256 + threadIdx.x;
  if (i < n) d[i] = (_Float16)s[i];
}
// Wp[l][j2][k] (j2<160: wm[l][j2][k], else wm[l][j2-160][160+k]); total 2*320*160
__global__ __launch_bounds__(256) void k_prep_wm(const float* __restrict__ wm,
                                                 _Float16* __restrict__ Wp) {
  int i = blockIdx.x * 256 + threadIdx.x;
  if (i >= 102400) return;
  int l = i / 51200, rem = i - l * 51200;
  int j2 = rem / 160, k = rem - j2 * 160;
  float v = (j2 < 160) ? wm[l * 51200 + j2 * 320 + k]
                       : wm[l * 51200 + (j2 - 160) * 320 + 160 + k];
  Wp[i] = (_Float16)v;
}

// ---------------------------------------------------------------- CSR build
__global__ __launch_bounds__(256) void k_count_i(const int* __restrict__ ei,
                                                 int* __restrict__ cnti) {
  int e = blockIdx.x * 256 + threadIdx.x;  // grid exact: 3125*256 = 800000
  atomicAdd(&cnti[ei[NE + e]], 1);
}

__global__ __launch_bounds__(256) void k_scan1(const int* __restrict__ cnti,
                                               int* __restrict__ off,
                                               int* __restrict__ bsum) {
  __shared__ int sh[256];
  const int t = threadIdx.x;
  const int i = blockIdx.x * 256 + t;  // grid 391 covers 100096
  int v = (i < NN) ? cnti[i] : 0;
  sh[t] = v;
  __syncthreads();
  for (int d = 1; d < 256; d <<= 1) {
    int add = (t >= d) ? sh[t - d] : 0;
    __syncthreads();
    sh[t] += add;
    __syncthreads();
  }
  if (i < NN) off[i] = sh[t] - v;  // exclusive within block
  if (t == 255) bsum[blockIdx.x] = sh[255];
}

__global__ __launch_bounds__(512) void k_scan2(const int* __restrict__ bsum,
                                               int* __restrict__ bsum2) {
  __shared__ int sh[512];
  const int t = threadIdx.x;
  int v = (t < 391) ? bsum[t] : 0;
  sh[t] = v;
  __syncthreads();
  for (int d = 1; d < 512; d <<= 1) {
    int add = (t >= d) ? sh[t - d] : 0;
    __syncthreads();
    sh[t] += add;
    __syncthreads();
  }
  if (t < 391) bsum2[t] = sh[t] - v;  // exclusive block offsets
}

__global__ __launch_bounds__(256) void k_scan3(int* __restrict__ off,
                                               const int* __restrict__ bsum2,
                                               int* __restrict__ cursor) {
  const int i = blockIdx.x * 256 + threadIdx.x;
  if (i < NN) {
    int o = off[i] + bsum2[blockIdx.x];
    off[i] = o;
    cursor[i] = o;
  }
  if (i == 0) off[NN] = NE;
}

__global__ __launch_bounds__(256) void k_scatter(const int* __restrict__ ei,
                                                 const float* __restrict__ ew,
                                                 int* __restrict__ cursor,
                                                 int2* __restrict__ selist) {
  int e = blockIdx.x * 256 + threadIdx.x;  // grid exact 3125
  int dst = ei[NE + e];
  int pos = atomicAdd(&cursor[dst], 1);
  selist[pos] = make_int2(ei[e], __float_as_int(ew[e]));
}

// ---------------------------------------------------------------- encoder (MFMA)
__global__ __launch_bounds__(256) void k_encode(
    const float* __restrict__ x, const float* __restrict__ tsp,
    const _Float16* __restrict__ We,
    const float* __restrict__ b_enc, const float* __restrict__ g_enc,
    const float* __restrict__ be_enc,
    const float* __restrict__ w_time, const float* __restrict__ b_time,
    const float* __restrict__ g_time, const float* __restrict__ be_time,
    float* __restrict__ h) {
  __shared__ _Float16 Ash[64 * 136];
  const int t = threadIdx.x;
  const int n0 = blockIdx.x * 64;  // grid 1563
#pragma unroll
  for (int r = 0; r < 8; ++r) {
    int q = t + r * 256;
    int nn = q >> 5, o = q & 31;
    int node = n0 + nn; if (node > NN - 1) node = NN - 1;
    float4 v = *(const float4*)&x[(size_t)node * 128 + o * 4];
    half4 hv = {(_Float16)v.x, (_Float16)v.y, (_Float16)v.z, (_Float16)v.w};
    *(half4*)&Ash[nn * 136 + o * 4] = hv;
  }
  __syncthreads();
  const int lane = t & 63, w = t >> 6;
  const int mrow = lane & 15, quad = lane >> 4;
  const int arow = w * 16 + mrow;
  floatx4 acc[8];
#pragma unroll
  for (int i = 0; i < 8; ++i) acc[i] = (floatx4)0.f;
  const _Float16* wbase = We + (size_t)mrow * 128 + quad * 8;
  for (int kt = 0; kt < 4; ++kt) {
    half8 a = *(const half8*)&Ash[arow * 136 + kt * 32 + quad * 8];
#pragma unroll
    for (int i = 0; i < 8; ++i) {
      half8 b = *(const half8*)&wbase[i * 16 * 128 + kt * 32];
      acc[i] = __builtin_amdgcn_mfma_f32_16x16x32_f16(a, b, acc[i], 0, 0, 0);
    }
  }
#pragma unroll
  for (int r = 0; r < 4; ++r) {
    const int row = quad * 4 + r;
    const int node = n0 + w * 16 + row;
    float v[8], s = 0.f, ss = 0.f;
#pragma unroll
    for (int i = 0; i < 8; ++i) {
      v[i] = acc[i][r] + b_enc[i * 16 + mrow];
      s += v[i]; ss = fmaf(v[i], v[i], ss);
    }
#pragma unroll
    for (int off = 1; off < 16; off <<= 1) { s += __shfl_xor(s, off); ss += __shfl_xor(ss, off); }
    const float m = s * (1.f / 128.f);
    const float var = ss * (1.f / 128.f) - m * m;
    const float rs = rsqrtf(var + 1e-5f);
    if (node < NN) {
#pragma unroll
      for (int i = 0; i < 8; ++i) {
        int j = i * 16 + mrow;
        h[(size_t)node * 160 + j] = fmaxf(fmaf((v[i] - m) * rs, g_enc[j], be_enc[j]), 0.f);
      }
    }
  }
  float mw = 0.f, mb = 0.f;
  for (int d = 0; d < 32; ++d) { mw += w_time[d]; mb += b_time[d]; }
  mw *= (1.f / 32.f); mb *= (1.f / 32.f);
  float A = 0.f, B = 0.f, C = 0.f;
  for (int d = 0; d < 32; ++d) {
    float a = w_time[d] - mw, c = b_time[d] - mb;
    A = fmaf(a, a, A); B = fmaf(a, c, B); C = fmaf(c, c, C);
  }
  A *= (1.f / 32.f); B *= (1.f / 32.f); C *= (1.f / 32.f);
#pragma unroll
  for (int r2 = 0; r2 < 8; ++r2) {
    int q = t + r2 * 256;
    int nn = q >> 5, d = q & 31;
    int node = n0 + nn;
    if (node < NN) {
      float tsv = tsp[node];
      float mt = fmaf(mw, tsv, mb);
      float vart = fmaf(fmaf(A, tsv, 2.f * B), tsv, C);
      float rst = rsqrtf(vart + 1e-5f);
      float vv = fmaf(w_time[d], tsv, b_time[d]);
      h[(size_t)node * 160 + 128 + d] = fmaxf(fmaf((vv - mt) * rst, g_time[d], be_time[d]), 0.f);
    }
  }
}

// ---------------------------------------------------------------- per-node projection (MFMA)
__global__ __launch_bounds__(256) void k_proj(
    const float* __restrict__ h, const _Float16* __restrict__ Wp,
    const float* __restrict__ bm, _Float16* __restrict__ P) {
  __shared__ _Float16 Ash[64 * 168];
  const int t = threadIdx.x;
  const int n0 = blockIdx.x * 64;  // grid 1563
#pragma unroll
  for (int r = 0; r < 10; ++r) {
    int q = t + r * 256;
    int nn = q / 40, o = q - nn * 40;
    int node = n0 + nn; if (node > NN - 1) node = NN - 1;
    float4 v = *(const float4*)&h[(size_t)node * 160 + o * 4];
    half4 hv = {(_Float16)v.x, (_Float16)v.y, (_Float16)v.z, (_Float16)v.w};
    *(half4*)&Ash[nn * 168 + o * 4] = hv;
  }
  __syncthreads();
  const int lane = t & 63, w = t >> 6;
  const int mrow = lane & 15, quad = lane >> 4;
  const int arow = w * 16 + mrow;
  floatx4 acc[20];
#pragma unroll
  for (int i = 0; i < 20; ++i) acc[i] = (floatx4)0.f;
  const _Float16* wbase = Wp + (size_t)mrow * 160 + quad * 8;
  for (int kt = 0; kt < 5; ++kt) {
    half8 a = *(const half8*)&Ash[arow * 168 + kt * 32 + quad * 8];
#pragma unroll
    for (int i = 0; i < 20; ++i) {
      half8 b = *(const half8*)&wbase[i * 16 * 160 + kt * 32];
      acc[i] = __builtin_amdgcn_mfma_f32_16x16x32_f16(a, b, acc[i], 0, 0, 0);
    }
  }
#pragma unroll
  for (int r = 0; r < 4; ++r) {
    const int row = quad * 4 + r;
    const int node = n0 + w * 16 + row;
    if (node < NN) {
      _Float16* prow = &P[(size_t)node * 320];
#pragma unroll
      for (int i = 0; i < 20; ++i) {
        int j2 = i * 16 + mrow;
        float v2 = acc[i][r] + ((j2 >= 160) ? bm[j2 - 160] : 0.f);
        prow[j2] = (_Float16)v2;
      }
    }
  }
}

// ---------------------------------------------------------------- edge aggregate (CSR, no atomics)
// 32-lane group per dst node; lane jg handles dims jg+32i (i<5); writes mean message.
__global__ __launch_bounds__(256) void k_edge3(
    const _Float16* __restrict__ P, const int* __restrict__ off,
    const int2* __restrict__ selist,
    const float* __restrict__ gm, const float* __restrict__ bem,
    float* __restrict__ msum) {
  const int t = threadIdx.x;
  const int jg = t & 31, g = t >> 5;
  const int n = blockIdx.x * 8 + g;  // grid exact: 12500*8 = 100000
  float gmv[5], bev[5], pdv[5];
#pragma unroll
  for (int i = 0; i < 5; ++i) { gmv[i] = gm[jg + 32 * i]; bev[i] = bem[jg + 32 * i]; }
  const _Float16* pd = P + (size_t)n * 320 + 160;
#pragma unroll
  for (int i = 0; i < 5; ++i) pdv[i] = (float)pd[jg + 32 * i];
  float acc[5] = {0.f, 0.f, 0.f, 0.f, 0.f};
  const int e0 = off[n], e1 = off[n + 1];
  for (int k = e0; k < e1; ++k) {
    int2 se = selist[k];
    const _Float16* ps = P + (size_t)se.x * 320;
    const float we = __int_as_float(se.y);
    float v[5], s = 0.f, ss = 0.f;
#pragma unroll
    for (int i = 0; i < 5; ++i) {
      v[i] = (float)ps[jg + 32 * i] + pdv[i];
      s += v[i]; ss = fmaf(v[i], v[i], ss);
    }
#pragma unroll
    for (int o = 1; o < 32; o <<= 1) { s += __shfl_xor(s, o); ss += __shfl_xor(ss, o); }
    const float m = s * (1.f / 160.f);
    const float var = ss * (1.f / 160.f) - m * m;
    const float rs = rsqrtf(var + 1e-5f);
#pragma unroll
    for (int i = 0; i < 5; ++i)
      acc[i] = fmaf(fmaxf(fmaf((v[i] - m) * rs, gmv[i], bev[i]), 0.f), we, acc[i]);
  }
  const float c = (float)(e1 - e0);
  const float ic = (c > 0.f) ? 1.f / (c + 1e-8f) : 0.f;
#pragma unroll
  for (int i = 0; i < 5; ++i) msum[(size_t)n * 160 + jg + 32 * i] = acc[i] * ic;
}

// ---------------------------------------------------------------- node update (MFMA) + gate
__global__ __launch_bounds__(256) void k_update(
    float* __restrict__ h, const float* __restrict__ msum,
    const _Float16* __restrict__ Wu, const float* __restrict__ bu,
    const float* __restrict__ gu, const float* __restrict__ beu,
    const float* __restrict__ wg, const float* __restrict__ bg) {
  __shared__ _Float16 Ash[64 * 328];
  const int t = threadIdx.x;
  const int n0 = blockIdx.x * 64;  // grid 1563
#pragma unroll
  for (int r = 0; r < 20; ++r) {
    int q = t + r * 256;
    int nn = q / 80, o = q - nn * 80;
    int node = n0 + nn; if (node > NN - 1) node = NN - 1;
    float4 v;
    if (o < 40) {
      v = *(const float4*)&h[(size_t)node * 160 + o * 4];
    } else {
      v = *(const float4*)&msum[(size_t)node * 160 + (o - 40) * 4];
    }
    half4 hv = {(_Float16)v.x, (_Float16)v.y, (_Float16)v.z, (_Float16)v.w};
    *(half4*)&Ash[nn * 328 + o * 4] = hv;
  }
  __syncthreads();
  const int lane = t & 63, w = t >> 6;
  const int mrow = lane & 15, quad = lane >> 4;
  const int arow = w * 16 + mrow;
  float gp = 0.f;
#pragma unroll
  for (int d = 0; d < 40; ++d)
    gp = fmaf(wg[quad * 40 + d], (float)Ash[arow * 328 + quad * 40 + d], gp);
  gp += __shfl_xor(gp, 16); gp += __shfl_xor(gp, 32);
  const float twv = 1.f / (1.f + expf(-(gp + bg[0])));
  floatx4 acc[10];
#pragma unroll
  for (int i = 0; i < 10; ++i) acc[i] = (floatx4)0.f;
  const _Float16* wbase = Wu + (size_t)mrow * 320 + quad * 8;
  for (int kt = 0; kt < 10; ++kt) {
    half8 a = *(const half8*)&Ash[arow * 328 + kt * 32 + quad * 8];
#pragma unroll
    for (int i = 0; i < 10; ++i) {
      half8 b = *(const half8*)&wbase[i * 16 * 320 + kt * 32];
      acc[i] = __builtin_amdgcn_mfma_f32_16x16x32_f16(a, b, acc[i], 0, 0, 0);
    }
  }
#pragma unroll
  for (int r = 0; r < 4; ++r) {
    const int row = quad * 4 + r;
    const int node = n0 + w * 16 + row;
    float v[10], s = 0.f, ss = 0.f;
#pragma unroll
    for (int i = 0; i < 10; ++i) {
      v[i] = acc[i][r] + bu[i * 16 + mrow];
      s += v[i]; ss = fmaf(v[i], v[i], ss);
    }
#pragma unroll
    for (int off = 1; off < 16; off <<= 1) { s += __shfl_xor(s, off); ss += __shfl_xor(ss, off); }
    const float m = s * (1.f / 160.f);
    const float var = ss * (1.f / 160.f) - m * m;
    const float rs = rsqrtf(var + 1e-5f);
    const float g = __shfl(twv, row);
    if (node < NN) {
      float* hrow = &h[(size_t)node * 160];
#pragma unroll
      for (int i = 0; i < 10; ++i) {
        int j = i * 16 + mrow;
        float hnew = fmaxf(fmaf((v[i] - m) * rs, gu[j], beu[j]), 0.f);
        float hold = hrow[j];
        hrow[j] = fmaf(g, hnew - hold, hold);
      }
    }
  }
}

// ---------------------------------------------------------------- output projection (MFMA) + L2 norm
__global__ __launch_bounds__(256) void k_out(
    const float* __restrict__ h, const _Float16* __restrict__ Wo,
    const float* __restrict__ b_out, float* __restrict__ out) {
  __shared__ _Float16 Ash[64 * 168];
  const int t = threadIdx.x;
  const int n0 = blockIdx.x * 64;  // grid 1563
#pragma unroll
  for (int r = 0; r < 10; ++r) {
    int q = t + r * 256;
    int nn = q / 40, o = q - nn * 40;
    int node = n0 + nn; if (node > NN - 1) node = NN - 1;
    float4 v = *(const float4*)&h[(size_t)node * 160 + o * 4];
    half4 hv = {(_Float16)v.x, (_Float16)v.y, (_Float16)v.z, (_Float16)v.w};
    *(half4*)&Ash[nn * 168 + o * 4] = hv;
  }
  __syncthreads();
  const int lane = t & 63, w = t >> 6;
  const int mrow = lane & 15, quad = lane >> 4;
  const int arow = w * 16 + mrow;
  floatx4 acc[8];
#pragma unroll
  for (int i = 0; i < 8; ++i) acc[i] = (floatx4)0.f;
  const _Float16* wbase = Wo + (size_t)mrow * 160 + quad * 8;
  for (int kt = 0; kt < 5; ++kt) {
    half8 a = *(const half8*)&Ash[arow * 168 + kt * 32 + quad * 8];
#pragma unroll
    for (int i = 0; i < 8; ++i) {
      half8 b = *(const half8*)&wbase[i * 16 * 160 + kt * 32];
      acc[i] = __builtin_amdgcn_mfma_f32_16x16x32_f16(a, b, acc[i], 0, 0, 0);
    }
  }
#pragma unroll
  for (int r = 0; r < 4; ++r) {
    const int row = quad * 4 + r;
    const int node = n0 + w * 16 + row;
    float v[8], ss = 0.f;
#pragma unroll
    for (int i = 0; i < 8; ++i) {
      v[i] = acc[i][r] + b_out[i * 16 + mrow];
      ss = fmaf(v[i], v[i], ss);
    }
#pragma unroll
    for (int off = 1; off < 16; off <<= 1) ss += __shfl_xor(ss, off);
    const float inv = 1.f / fmaxf(sqrtf(ss), 1e-12f);
    if (node < NN) {
#pragma unroll
      for (int i = 0; i < 8; ++i)
        out[(size_t)node * 128 + i * 16 + mrow] = v[i] * inv;
    }
  }
}

// ---------------------------------------------------------------- launch
extern "C" void kernel_launch(void* const* d_in, const int* in_sizes, int n_in,
                              void* d_out, int out_size, void* d_ws, size_t ws_size,
                              hipStream_t stream) {
  (void)in_sizes; (void)n_in; (void)out_size; (void)ws_size;
  const float* x       = (const float*)d_in[0];
  const int*   ei      = (const int*)  d_in[1];
  const float* ew      = (const float*)d_in[2];
  const float* tsp     = (const float*)d_in[3];
  const float* w_enc   = (const float*)d_in[4];
  const float* b_enc   = (const float*)d_in[5];
  const float* g_enc   = (const float*)d_in[6];
  const float* be_enc  = (const float*)d_in[7];
  const float* w_time  = (const float*)d_in[8];
  const float* b_time  = (const float*)d_in[9];
  const float* g_time  = (const float*)d_in[10];
  const float* be_time = (const float*)d_in[11];
  const float* wm      = (const float*)d_in[12];
  const float* bm      = (const float*)d_in[13];
  const float* gm      = (const float*)d_in[14];
  const float* bem     = (const float*)d_in[15];
  const float* wu      = (const float*)d_in[16];
  const float* bu      = (const float*)d_in[17];
  const float* gu      = (const float*)d_in[18];
  const float* beu     = (const float*)d_in[19];
  const float* wg      = (const float*)d_in[20];
  const float* bg      = (const float*)d_in[21];
  const float* w_out   = (const float*)d_in[22];
  const float* b_out   = (const float*)d_in[23];
  float* out = (float*)d_out;

  // ws layout (bytes): h f32[NN*160] @0 (64M) | msum f32[NN*160] @64,000,000 (64M)
  //                    P f16[NN*320] @128,000,000 (64M) | Wo16 @192,000,000 (40,960)
  //   total 192,040,960 (fits: round-2/3 used 192.44 MB)
  char* ws = (char*)d_ws;
  float* h    = (float*)ws;
  float* msum = (float*)(ws + 64000000);
  _Float16* P    = (_Float16*)(ws + 128000000);
  _Float16* Wo16 = (_Float16*)(ws + 192000000);
  // d_out doubles as scratch until k_out overwrites all of it (51.2 MB):
  //   Wp16 @0 (204,800) | Wu16 @204,800 (204,800) | We16 @409,600 (32,768)
  //   off int[NN+1] @442,368 (400,016 w/ pad) | cnti @842,384 (400,000)
  //   cursor @1,242,384 (400,000) | bsum @1,642,384 (1,568) | bsum2 @1,643,952 (1,568)
  //   selist int2[NE] @1,645,520 (6,400,000) -> 8,045,520 < 51,200,000
  char* ob = (char*)d_out;
  _Float16* Wp16 = (_Float16*)ob;
  _Float16* Wu16 = (_Float16*)(ob + 204800);
  _Float16* We16 = (_Float16*)(ob + 409600);
  int* off    = (int*)(ob + 442368);
  int* cnti   = (int*)(ob + 842384);
  int* cursor = (int*)(ob + 1242384);
  int* bsum   = (int*)(ob + 1642384);
  int* bsum2  = (int*)(ob + 1643952);
  int2* selist = (int2*)(ob + 1645520);

  // weight prep + CSR build (edges static across layers: build once)
  k_zero<<<dim3(98), dim3(256), 0, stream>>>((float4*)cnti, 25000);  // 100k ints
  k_cast<<<dim3(400), dim3(256), 0, stream>>>(wu, Wu16, 102400);
  k_cast<<<dim3(64),  dim3(256), 0, stream>>>(w_enc, We16, 16384);
  k_cast<<<dim3(80),  dim3(256), 0, stream>>>(w_out, Wo16, 20480);
  k_prep_wm<<<dim3(400), dim3(256), 0, stream>>>(wm, Wp16);
  k_count_i<<<dim3(3125), dim3(256), 0, stream>>>(ei, cnti);
  k_scan1<<<dim3(391), dim3(256), 0, stream>>>(cnti, off, bsum);
  k_scan2<<<dim3(1), dim3(512), 0, stream>>>(bsum, bsum2);
  k_scan3<<<dim3(391), dim3(256), 0, stream>>>(off, bsum2, cursor);
  k_scatter<<<dim3(3125), dim3(256), 0, stream>>>(ei, ew, cursor, selist);

  k_encode<<<dim3(1563), dim3(256), 0, stream>>>(x, tsp, We16, b_enc, g_enc, be_enc,
                                                 w_time, b_time, g_time, be_time, h);
  for (int l = 0; l < 2; ++l) {
    k_proj<<<dim3(1563), dim3(256), 0, stream>>>(h, Wp16 + (size_t)l * 51200, bm + l * 160, P);
    k_edge3<<<dim3(12500), dim3(256), 0, stream>>>(P, off, selist,
                                                   gm + l * 160, bem + l * 160, msum);
    k_update<<<dim3(1563), dim3(256), 0, stream>>>(h, msum,
        Wu16 + (size_t)l * 51200, bu + l * 160, gu + l * 160, beu + l * 160,
        wg + l * 160, bg + l);
  }
  k_out<<<dim3(1563), dim3(256), 0, stream>>>(h, Wo16, b_out, out);
}

// Round 5
// 838.549 us; speedup vs baseline: 7.9171x; 1.0327x over previous
//
#include <hip/hip_runtime.h>

#define NN 100000
#define NE 800000
// D = 160, 2D = 320, F = 128

typedef _Float16 half8 __attribute__((ext_vector_type(8)));
typedef _Float16 half4 __attribute__((ext_vector_type(4)));
typedef float floatx4 __attribute__((ext_vector_type(4)));

// ---------------------------------------------------------------- zero
__global__ __launch_bounds__(256) void k_zero(float4* __restrict__ p, int n4) {
  int i = blockIdx.x * 256 + threadIdx.x;
  if (i < n4) p[i] = make_float4(0.f, 0.f, 0.f, 0.f);
}

// ---------------------------------------------------------------- weight casts
__global__ __launch_bounds__(256) void k_cast(const float* __restrict__ s,
                                              _Float16* __restrict__ d, int n) {
  int i = blockIdx.x * 256 + threadIdx.x;
  if (i < n) d[i] = (_Float16)s[i];
}
// Wp[l][j2][k] (j2<160: wm[l][j2][k], else wm[l][j2-160][160+k]); total 2*320*160
__global__ __launch_bounds__(256) void k_prep_wm(const float* __restrict__ wm,
                                                 _Float16* __restrict__ Wp) {
  int i = blockIdx.x * 256 + threadIdx.x;
  if (i >= 102400) return;
  int l = i / 51200, rem = i - l * 51200;
  int j2 = rem / 160, k = rem - j2 * 160;
  float v = (j2 < 160) ? wm[l * 51200 + j2 * 320 + k]
                       : wm[l * 51200 + (j2 - 160) * 320 + 160 + k];
  Wp[i] = (_Float16)v;
}

// ---------------------------------------------------------------- CSR build
__global__ __launch_bounds__(256) void k_count_i(const int* __restrict__ ei,
                                                 int* __restrict__ cnti) {
  int e = blockIdx.x * 256 + threadIdx.x;  // grid exact: 3125*256 = 800000
  atomicAdd(&cnti[ei[NE + e]], 1);
}

__global__ __launch_bounds__(256) void k_scan1(const int* __restrict__ cnti,
                                               int* __restrict__ off,
                                               int* __restrict__ bsum) {
  __shared__ int sh[256];
  const int t = threadIdx.x;
  const int i = blockIdx.x * 256 + t;  // grid 391 covers 100096
  int v = (i < NN) ? cnti[i] : 0;
  sh[t] = v;
  __syncthreads();
  for (int d = 1; d < 256; d <<= 1) {
    int add = (t >= d) ? sh[t - d] : 0;
    __syncthreads();
    sh[t] += add;
    __syncthreads();
  }
  if (i < NN) off[i] = sh[t] - v;
  if (t == 255) bsum[blockIdx.x] = sh[255];
}

__global__ __launch_bounds__(512) void k_scan2(const int* __restrict__ bsum,
                                               int* __restrict__ bsum2) {
  __shared__ int sh[512];
  const int t = threadIdx.x;
  int v = (t < 391) ? bsum[t] : 0;
  sh[t] = v;
  __syncthreads();
  for (int d = 1; d < 512; d <<= 1) {
    int add = (t >= d) ? sh[t - d] : 0;
    __syncthreads();
    sh[t] += add;
    __syncthreads();
  }
  if (t < 391) bsum2[t] = sh[t] - v;
}

__global__ __launch_bounds__(256) void k_scan3(int* __restrict__ off,
                                               const int* __restrict__ bsum2,
                                               int* __restrict__ cursor) {
  const int i = blockIdx.x * 256 + threadIdx.x;
  if (i < NN) {
    int o = off[i] + bsum2[blockIdx.x];
    off[i] = o;
    cursor[i] = o;
  }
  if (i == 0) off[NN] = NE;
}

__global__ __launch_bounds__(256) void k_scatter(const int* __restrict__ ei,
                                                 const float* __restrict__ ew,
                                                 int* __restrict__ cursor,
                                                 int2* __restrict__ selist) {
  int e = blockIdx.x * 256 + threadIdx.x;  // grid exact 3125
  int dst = ei[NE + e];
  int pos = atomicAdd(&cursor[dst], 1);
  selist[pos] = make_int2(ei[e], __float_as_int(ew[e]));
}

// ---------------------------------------------------------------- encoder (MFMA, no LDS)
__global__ __launch_bounds__(256) void k_encode(
    const float* __restrict__ x, const float* __restrict__ tsp,
    const _Float16* __restrict__ We,
    const float* __restrict__ b_enc, const float* __restrict__ g_enc,
    const float* __restrict__ be_enc,
    const float* __restrict__ w_time, const float* __restrict__ b_time,
    const float* __restrict__ g_time, const float* __restrict__ be_time,
    float* __restrict__ h) {
  const int t = threadIdx.x;
  const int lane = t & 63, w = t >> 6;
  const int mrow = lane & 15, quad = lane >> 4;
  const int n0 = blockIdx.x * 64;  // grid 1563
  int arow = n0 + w * 16 + mrow; if (arow > NN - 1) arow = NN - 1;
  const float* xrow = x + (size_t)arow * 128;
  floatx4 acc[8];
#pragma unroll
  for (int i = 0; i < 8; ++i) acc[i] = (floatx4)0.f;
  const _Float16* wbase = We + (size_t)mrow * 128 + quad * 8;
#pragma unroll
  for (int kt = 0; kt < 4; ++kt) {
    const int k0 = kt * 32 + quad * 8;
    float4 f0 = *(const float4*)&xrow[k0];
    float4 f1 = *(const float4*)&xrow[k0 + 4];
    half8 a = {(_Float16)f0.x, (_Float16)f0.y, (_Float16)f0.z, (_Float16)f0.w,
               (_Float16)f1.x, (_Float16)f1.y, (_Float16)f1.z, (_Float16)f1.w};
#pragma unroll
    for (int i = 0; i < 8; ++i) {
      half8 b = *(const half8*)&wbase[i * 16 * 128 + kt * 32];
      acc[i] = __builtin_amdgcn_mfma_f32_16x16x32_f16(a, b, acc[i], 0, 0, 0);
    }
  }
#pragma unroll
  for (int r = 0; r < 4; ++r) {
    const int row = quad * 4 + r;
    const int node = n0 + w * 16 + row;
    float v[8], s = 0.f, ss = 0.f;
#pragma unroll
    for (int i = 0; i < 8; ++i) {
      v[i] = acc[i][r] + b_enc[i * 16 + mrow];
      s += v[i]; ss = fmaf(v[i], v[i], ss);
    }
#pragma unroll
    for (int off = 1; off < 16; off <<= 1) { s += __shfl_xor(s, off); ss += __shfl_xor(ss, off); }
    const float m = s * (1.f / 128.f);
    const float var = ss * (1.f / 128.f) - m * m;
    const float rs = rsqrtf(var + 1e-5f);
    if (node < NN) {
#pragma unroll
      for (int i = 0; i < 8; ++i) {
        int j = i * 16 + mrow;
        h[(size_t)node * 160 + j] = fmaxf(fmaf((v[i] - m) * rs, g_enc[j], be_enc[j]), 0.f);
      }
    }
  }
  // time dims 128..159, closed-form LN
  float mw = 0.f, mb = 0.f;
  for (int d = 0; d < 32; ++d) { mw += w_time[d]; mb += b_time[d]; }
  mw *= (1.f / 32.f); mb *= (1.f / 32.f);
  float A = 0.f, B = 0.f, C = 0.f;
  for (int d = 0; d < 32; ++d) {
    float a = w_time[d] - mw, c = b_time[d] - mb;
    A = fmaf(a, a, A); B = fmaf(a, c, B); C = fmaf(c, c, C);
  }
  A *= (1.f / 32.f); B *= (1.f / 32.f); C *= (1.f / 32.f);
#pragma unroll
  for (int r2 = 0; r2 < 8; ++r2) {
    int q = t + r2 * 256;  // 2048 = 64 nodes x 32 dims
    int nn = q >> 5, d = q & 31;
    int node = n0 + nn;
    if (node < NN) {
      float tsv = tsp[node];
      float mt = fmaf(mw, tsv, mb);
      float vart = fmaf(fmaf(A, tsv, 2.f * B), tsv, C);
      float rst = rsqrtf(vart + 1e-5f);
      float vv = fmaf(w_time[d], tsv, b_time[d]);
      h[(size_t)node * 160 + 128 + d] = fmaxf(fmaf((vv - mt) * rst, g_time[d], be_time[d]), 0.f);
    }
  }
}

// ---------------------------------------------------------------- per-node projection (MFMA, no LDS)
__global__ __launch_bounds__(256) void k_proj(
    const float* __restrict__ h, const _Float16* __restrict__ Wp,
    const float* __restrict__ bm, _Float16* __restrict__ P) {
  const int t = threadIdx.x;
  const int lane = t & 63, w = t >> 6;
  const int mrow = lane & 15, quad = lane >> 4;
  const int n0 = blockIdx.x * 64;  // grid 1563
  int arow = n0 + w * 16 + mrow; if (arow > NN - 1) arow = NN - 1;
  const float* hrow = h + (size_t)arow * 160;
  floatx4 acc[20];
#pragma unroll
  for (int i = 0; i < 20; ++i) acc[i] = (floatx4)0.f;
  const _Float16* wbase = Wp + (size_t)mrow * 160 + quad * 8;
#pragma unroll
  for (int kt = 0; kt < 5; ++kt) {
    const int k0 = kt * 32 + quad * 8;
    float4 f0 = *(const float4*)&hrow[k0];
    float4 f1 = *(const float4*)&hrow[k0 + 4];
    half8 a = {(_Float16)f0.x, (_Float16)f0.y, (_Float16)f0.z, (_Float16)f0.w,
               (_Float16)f1.x, (_Float16)f1.y, (_Float16)f1.z, (_Float16)f1.w};
#pragma unroll
    for (int i = 0; i < 20; ++i) {
      half8 b = *(const half8*)&wbase[i * 16 * 160 + kt * 32];
      acc[i] = __builtin_amdgcn_mfma_f32_16x16x32_f16(a, b, acc[i], 0, 0, 0);
    }
  }
#pragma unroll
  for (int r = 0; r < 4; ++r) {
    const int row = quad * 4 + r;
    const int node = n0 + w * 16 + row;
    if (node < NN) {
      _Float16* prow = &P[(size_t)node * 320];
#pragma unroll
      for (int i = 0; i < 20; ++i) {
        int j2 = i * 16 + mrow;
        float v2 = acc[i][r] + ((j2 >= 160) ? bm[j2 - 160] : 0.f);
        prow[j2] = (_Float16)v2;
      }
    }
  }
}

// ---------------------------------------------------------------- edge aggregate (CSR, no atomics)
// 32-lane group per dst node; lane jg owns dims {4jg..4jg+3, 128+jg}; writes f16 mean.
__global__ __launch_bounds__(256) void k_edge3(
    const _Float16* __restrict__ P, const int* __restrict__ off,
    const int2* __restrict__ selist,
    const float* __restrict__ gm, const float* __restrict__ bem,
    _Float16* __restrict__ msum16) {
  const int t = threadIdx.x;
  const int jg = t & 31, g = t >> 5;
  const int n = blockIdx.x * 8 + g;  // grid exact: 12500*8 = 100000
  float gmv[5], bev[5], pdv[5];
#pragma unroll
  for (int i = 0; i < 4; ++i) { gmv[i] = gm[4 * jg + i]; bev[i] = bem[4 * jg + i]; }
  gmv[4] = gm[128 + jg]; bev[4] = bem[128 + jg];
  const _Float16* pd = P + (size_t)n * 320 + 160;
  half4 pdh = *(const half4*)&pd[4 * jg];
  pdv[0] = (float)pdh.x; pdv[1] = (float)pdh.y; pdv[2] = (float)pdh.z; pdv[3] = (float)pdh.w;
  pdv[4] = (float)pd[128 + jg];
  float acc[5] = {0.f, 0.f, 0.f, 0.f, 0.f};
  const int e0 = off[n], e1 = off[n + 1];
  for (int k = e0; k < e1; ++k) {
    int2 se = selist[k];
    const _Float16* ps = P + (size_t)se.x * 320;
    const float we = __int_as_float(se.y);
    half4 s4 = *(const half4*)&ps[4 * jg];
    float v[5], s = 0.f, ss = 0.f;
    v[0] = (float)s4.x + pdv[0]; v[1] = (float)s4.y + pdv[1];
    v[2] = (float)s4.z + pdv[2]; v[3] = (float)s4.w + pdv[3];
    v[4] = (float)ps[128 + jg] + pdv[4];
#pragma unroll
    for (int i = 0; i < 5; ++i) { s += v[i]; ss = fmaf(v[i], v[i], ss); }
#pragma unroll
    for (int o = 1; o < 32; o <<= 1) { s += __shfl_xor(s, o); ss += __shfl_xor(ss, o); }
    const float m = s * (1.f / 160.f);
    const float var = ss * (1.f / 160.f) - m * m;
    const float rs = rsqrtf(var + 1e-5f);
#pragma unroll
    for (int i = 0; i < 5; ++i)
      acc[i] = fmaf(fmaxf(fmaf((v[i] - m) * rs, gmv[i], bev[i]), 0.f), we, acc[i]);
  }
  const float c = (float)(e1 - e0);
  const float ic = (c > 0.f) ? 1.f / (c + 1e-8f) : 0.f;
  _Float16* orow = msum16 + (size_t)n * 160;
  half4 o4 = {(_Float16)(acc[0] * ic), (_Float16)(acc[1] * ic),
              (_Float16)(acc[2] * ic), (_Float16)(acc[3] * ic)};
  *(half4*)&orow[4 * jg] = o4;
  orow[128 + jg] = (_Float16)(acc[4] * ic);
}

// ---------------------------------------------------------------- node update (MFMA, no LDS) + gate
__global__ __launch_bounds__(256) void k_update(
    float* __restrict__ h, const _Float16* __restrict__ msum16,
    const _Float16* __restrict__ Wu, const float* __restrict__ bu,
    const float* __restrict__ gu, const float* __restrict__ beu,
    const float* __restrict__ wg, const float* __restrict__ bg) {
  const int t = threadIdx.x;
  const int lane = t & 63, w = t >> 6;
  const int mrow = lane & 15, quad = lane >> 4;
  const int n0 = blockIdx.x * 64;  // grid 1563
  int arow = n0 + w * 16 + mrow; if (arow > NN - 1) arow = NN - 1;
  const float* hrowp = h + (size_t)arow * 160;
  const _Float16* mrowp = msum16 + (size_t)arow * 160;
  floatx4 acc[10];
#pragma unroll
  for (int i = 0; i < 10; ++i) acc[i] = (floatx4)0.f;
  const _Float16* wbase = Wu + (size_t)mrow * 320 + quad * 8;
  float gp = 0.f;
  // kt 0..4: A from h (f32->f16), fold gate dot in
#pragma unroll
  for (int kt = 0; kt < 5; ++kt) {
    const int k0 = kt * 32 + quad * 8;
    float4 f0 = *(const float4*)&hrowp[k0];
    float4 f1 = *(const float4*)&hrowp[k0 + 4];
    float4 g0 = *(const float4*)&wg[k0];
    float4 g1 = *(const float4*)&wg[k0 + 4];
    gp = fmaf(f0.x, g0.x, gp); gp = fmaf(f0.y, g0.y, gp);
    gp = fmaf(f0.z, g0.z, gp); gp = fmaf(f0.w, g0.w, gp);
    gp = fmaf(f1.x, g1.x, gp); gp = fmaf(f1.y, g1.y, gp);
    gp = fmaf(f1.z, g1.z, gp); gp = fmaf(f1.w, g1.w, gp);
    half8 a = {(_Float16)f0.x, (_Float16)f0.y, (_Float16)f0.z, (_Float16)f0.w,
               (_Float16)f1.x, (_Float16)f1.y, (_Float16)f1.z, (_Float16)f1.w};
#pragma unroll
    for (int i = 0; i < 10; ++i) {
      half8 b = *(const half8*)&wbase[i * 16 * 320 + kt * 32];
      acc[i] = __builtin_amdgcn_mfma_f32_16x16x32_f16(a, b, acc[i], 0, 0, 0);
    }
  }
  // kt 5..9: A from msum16 (f16 direct)
#pragma unroll
  for (int kt = 5; kt < 10; ++kt) {
    const int k0 = kt * 32 + quad * 8 - 160;
    half8 a = *(const half8*)&mrowp[k0];
#pragma unroll
    for (int i = 0; i < 10; ++i) {
      half8 b = *(const half8*)&wbase[i * 16 * 320 + kt * 32];
      acc[i] = __builtin_amdgcn_mfma_f32_16x16x32_f16(a, b, acc[i], 0, 0, 0);
    }
  }
  gp += __shfl_xor(gp, 16); gp += __shfl_xor(gp, 32);
  const float twv = 1.f / (1.f + expf(-(gp + bg[0])));
#pragma unroll
  for (int r = 0; r < 4; ++r) {
    const int row = quad * 4 + r;
    const int node = n0 + w * 16 + row;
    float v[10], s = 0.f, ss = 0.f;
#pragma unroll
    for (int i = 0; i < 10; ++i) {
      v[i] = acc[i][r] + bu[i * 16 + mrow];
      s += v[i]; ss = fmaf(v[i], v[i], ss);
    }
#pragma unroll
    for (int off = 1; off < 16; off <<= 1) { s += __shfl_xor(s, off); ss += __shfl_xor(ss, off); }
    const float m = s * (1.f / 160.f);
    const float var = ss * (1.f / 160.f) - m * m;
    const float rs = rsqrtf(var + 1e-5f);
    const float g = __shfl(twv, row);
    if (node < NN) {
      float* hrow = &h[(size_t)node * 160];
#pragma unroll
      for (int i = 0; i < 10; ++i) {
        int j = i * 16 + mrow;
        float hnew = fmaxf(fmaf((v[i] - m) * rs, gu[j], beu[j]), 0.f);
        float hold = hrow[j];
        hrow[j] = fmaf(g, hnew - hold, hold);
      }
    }
  }
}

// ---------------------------------------------------------------- output projection (MFMA, no LDS) + L2 norm
__global__ __launch_bounds__(256) void k_out(
    const float* __restrict__ h, const _Float16* __restrict__ Wo,
    const float* __restrict__ b_out, float* __restrict__ out) {
  const int t = threadIdx.x;
  const int lane = t & 63, w = t >> 6;
  const int mrow = lane & 15, quad = lane >> 4;
  const int n0 = blockIdx.x * 64;  // grid 1563
  int arow = n0 + w * 16 + mrow; if (arow > NN - 1) arow = NN - 1;
  const float* hrow = h + (size_t)arow * 160;
  floatx4 acc[8];
#pragma unroll
  for (int i = 0; i < 8; ++i) acc[i] = (floatx4)0.f;
  const _Float16* wbase = Wo + (size_t)mrow * 160 + quad * 8;
#pragma unroll
  for (int kt = 0; kt < 5; ++kt) {
    const int k0 = kt * 32 + quad * 8;
    float4 f0 = *(const float4*)&hrow[k0];
    float4 f1 = *(const float4*)&hrow[k0 + 4];
    half8 a = {(_Float16)f0.x, (_Float16)f0.y, (_Float16)f0.z, (_Float16)f0.w,
               (_Float16)f1.x, (_Float16)f1.y, (_Float16)f1.z, (_Float16)f1.w};
#pragma unroll
    for (int i = 0; i < 8; ++i) {
      half8 b = *(const half8*)&wbase[i * 16 * 160 + kt * 32];
      acc[i] = __builtin_amdgcn_mfma_f32_16x16x32_f16(a, b, acc[i], 0, 0, 0);
    }
  }
#pragma unroll
  for (int r = 0; r < 4; ++r) {
    const int row = quad * 4 + r;
    const int node = n0 + w * 16 + row;
    float v[8], ss = 0.f;
#pragma unroll
    for (int i = 0; i < 8; ++i) {
      v[i] = acc[i][r] + b_out[i * 16 + mrow];
      ss = fmaf(v[i], v[i], ss);
    }
#pragma unroll
    for (int off = 1; off < 16; off <<= 1) ss += __shfl_xor(ss, off);
    const float inv = 1.f / fmaxf(sqrtf(ss), 1e-12f);
    if (node < NN) {
#pragma unroll
      for (int i = 0; i < 8; ++i)
        out[(size_t)node * 128 + i * 16 + mrow] = v[i] * inv;
    }
  }
}

// ---------------------------------------------------------------- launch
extern "C" void kernel_launch(void* const* d_in, const int* in_sizes, int n_in,
                              void* d_out, int out_size, void* d_ws, size_t ws_size,
                              hipStream_t stream) {
  (void)in_sizes; (void)n_in; (void)out_size; (void)ws_size;
  const float* x       = (const float*)d_in[0];
  const int*   ei      = (const int*)  d_in[1];
  const float* ew      = (const float*)d_in[2];
  const float* tsp     = (const float*)d_in[3];
  const float* w_enc   = (const float*)d_in[4];
  const float* b_enc   = (const float*)d_in[5];
  const float* g_enc   = (const float*)d_in[6];
  const float* be_enc  = (const float*)d_in[7];
  const float* w_time  = (const float*)d_in[8];
  const float* b_time  = (const float*)d_in[9];
  const float* g_time  = (const float*)d_in[10];
  const float* be_time = (const float*)d_in[11];
  const float* wm      = (const float*)d_in[12];
  const float* bm      = (const float*)d_in[13];
  const float* gm      = (const float*)d_in[14];
  const float* bem     = (const float*)d_in[15];
  const float* wu      = (const float*)d_in[16];
  const float* bu      = (const float*)d_in[17];
  const float* gu      = (const float*)d_in[18];
  const float* beu     = (const float*)d_in[19];
  const float* wg      = (const float*)d_in[20];
  const float* bg      = (const float*)d_in[21];
  const float* w_out   = (const float*)d_in[22];
  const float* b_out   = (const float*)d_in[23];
  float* out = (float*)d_out;

  // ws layout (bytes): h f32[NN*160] @0 (64M) | msum16 f16[NN*160] @64,000,000 (32M)
  //                    P f16[NN*320] @96,000,000 (64M) | Wo16 @160,000,000 (40,960)
  //   total 160,040,960 < 192,440,960 used in earlier passing rounds
  char* ws = (char*)d_ws;
  float* h          = (float*)ws;
  _Float16* msum16  = (_Float16*)(ws + 64000000);
  _Float16* P       = (_Float16*)(ws + 96000000);
  _Float16* Wo16    = (_Float16*)(ws + 160000000);
  // d_out doubles as scratch until k_out overwrites all of it (51.2 MB):
  char* ob = (char*)d_out;
  _Float16* Wp16 = (_Float16*)ob;
  _Float16* Wu16 = (_Float16*)(ob + 204800);
  _Float16* We16 = (_Float16*)(ob + 409600);
  int* off    = (int*)(ob + 442368);
  int* cnti   = (int*)(ob + 842384);
  int* cursor = (int*)(ob + 1242384);
  int* bsum   = (int*)(ob + 1642384);
  int* bsum2  = (int*)(ob + 1643952);
  int2* selist = (int2*)(ob + 1645520);

  // weight prep + CSR build (edges static across layers: build once)
  k_zero<<<dim3(98), dim3(256), 0, stream>>>((float4*)cnti, 25000);
  k_cast<<<dim3(400), dim3(256), 0, stream>>>(wu, Wu16, 102400);
  k_cast<<<dim3(64),  dim3(256), 0, stream>>>(w_enc, We16, 16384);
  k_cast<<<dim3(80),  dim3(256), 0, stream>>>(w_out, Wo16, 20480);
  k_prep_wm<<<dim3(400), dim3(256), 0, stream>>>(wm, Wp16);
  k_count_i<<<dim3(3125), dim3(256), 0, stream>>>(ei, cnti);
  k_scan1<<<dim3(391), dim3(256), 0, stream>>>(cnti, off, bsum);
  k_scan2<<<dim3(1), dim3(512), 0, stream>>>(bsum, bsum2);
  k_scan3<<<dim3(391), dim3(256), 0, stream>>>(off, bsum2, cursor);
  k_scatter<<<dim3(3125), dim3(256), 0, stream>>>(ei, ew, cursor, selist);

  k_encode<<<dim3(1563), dim3(256), 0, stream>>>(x, tsp, We16, b_enc, g_enc, be_enc,
                                                 w_time, b_time, g_time, be_time, h);
  for (int l = 0; l < 2; ++l) {
    k_proj<<<dim3(1563), dim3(256), 0, stream>>>(h, Wp16 + (size_t)l * 51200, bm + l * 160, P);
    k_edge3<<<dim3(12500), dim3(256), 0, stream>>>(P, off, selist,
                                                   gm + l * 160, bem + l * 160, msum16);
    k_update<<<dim3(1563), dim3(256), 0, stream>>>(h, msum16,
        Wu16 + (size_t)l * 51200, bu + l * 160, gu + l * 160, beu + l * 160,
        wg + l * 160, bg + l);
  }
  k_out<<<dim3(1563), dim3(256), 0, stream>>>(h, Wo16, b_out, out);
}

// Round 6
// 800.536 us; speedup vs baseline: 8.2930x; 1.0475x over previous
//
#include <hip/hip_runtime.h>

#define NN 100000
#define NE 800000
// D = 160, 2D = 320, F = 128

typedef _Float16 half8 __attribute__((ext_vector_type(8)));
typedef _Float16 half4 __attribute__((ext_vector_type(4)));
typedef float floatx4 __attribute__((ext_vector_type(4)));

// ---------------------------------------------------------------- zero
__global__ __launch_bounds__(256) void k_zero(float4* __restrict__ p, int n4) {
  int i = blockIdx.x * 256 + threadIdx.x;
  if (i < n4) p[i] = make_float4(0.f, 0.f, 0.f, 0.f);
}

// ---------------------------------------------------------------- weight casts
__global__ __launch_bounds__(256) void k_cast(const float* __restrict__ s,
                                              _Float16* __restrict__ d, int n) {
  int i = blockIdx.x * 256 + threadIdx.x;
  if (i < n) d[i] = (_Float16)s[i];
}
// Wp[l][j2][k] (j2<160: wm[l][j2][k], else wm[l][j2-160][160+k]); total 2*320*160
__global__ __launch_bounds__(256) void k_prep_wm(const float* __restrict__ wm,
                                                 _Float16* __restrict__ Wp) {
  int i = blockIdx.x * 256 + threadIdx.x;
  if (i >= 102400) return;
  int l = i / 51200, rem = i - l * 51200;
  int j2 = rem / 160, k = rem - j2 * 160;
  float v = (j2 < 160) ? wm[l * 51200 + j2 * 320 + k]
                       : wm[l * 51200 + (j2 - 160) * 320 + 160 + k];
  Wp[i] = (_Float16)v;
}

// ---------------------------------------------------------------- CSR build
__global__ __launch_bounds__(256) void k_count_i(const int* __restrict__ ei,
                                                 int* __restrict__ cnti) {
  int e = blockIdx.x * 256 + threadIdx.x;  // grid exact: 3125*256 = 800000
  atomicAdd(&cnti[ei[NE + e]], 1);
}

__global__ __launch_bounds__(256) void k_scan1(const int* __restrict__ cnti,
                                               int* __restrict__ off,
                                               int* __restrict__ bsum) {
  __shared__ int sh[256];
  const int t = threadIdx.x;
  const int i = blockIdx.x * 256 + t;  // grid 391 covers 100096
  int v = (i < NN) ? cnti[i] : 0;
  sh[t] = v;
  __syncthreads();
  for (int d = 1; d < 256; d <<= 1) {
    int add = (t >= d) ? sh[t - d] : 0;
    __syncthreads();
    sh[t] += add;
    __syncthreads();
  }
  if (i < NN) off[i] = sh[t] - v;
  if (t == 255) bsum[blockIdx.x] = sh[255];
}

__global__ __launch_bounds__(512) void k_scan2(const int* __restrict__ bsum,
                                               int* __restrict__ bsum2) {
  __shared__ int sh[512];
  const int t = threadIdx.x;
  int v = (t < 391) ? bsum[t] : 0;
  sh[t] = v;
  __syncthreads();
  for (int d = 1; d < 512; d <<= 1) {
    int add = (t >= d) ? sh[t - d] : 0;
    __syncthreads();
    sh[t] += add;
    __syncthreads();
  }
  if (t < 391) bsum2[t] = sh[t] - v;
}

__global__ __launch_bounds__(256) void k_scan3(int* __restrict__ off,
                                               const int* __restrict__ bsum2,
                                               int* __restrict__ cursor) {
  const int i = blockIdx.x * 256 + threadIdx.x;
  if (i < NN) {
    int o = off[i] + bsum2[blockIdx.x];
    off[i] = o;
    cursor[i] = o;
  }
  if (i == 0) off[NN] = NE;
}

__global__ __launch_bounds__(256) void k_scatter(const int* __restrict__ ei,
                                                 const float* __restrict__ ew,
                                                 int* __restrict__ cursor,
                                                 int2* __restrict__ selist) {
  int e = blockIdx.x * 256 + threadIdx.x;  // grid exact 3125
  int dst = ei[NE + e];
  int pos = atomicAdd(&cursor[dst], 1);
  selist[pos] = make_int2(ei[e], __float_as_int(ew[e]));
}

// ---------------------------------------------------------------- fused encoder + proj
// phase1: h[n,:] = [relu(LN(x@We^T+b)), time-LN]  -> global h32 + LDS f16 tile
// phase2: P[n,:] = tile @ Wp^T (+bm on cols>=160)
__global__ __launch_bounds__(256) void k_encode_proj(
    const float* __restrict__ x, const float* __restrict__ tsp,
    const _Float16* __restrict__ We,
    const float* __restrict__ b_enc, const float* __restrict__ g_enc,
    const float* __restrict__ be_enc,
    const float* __restrict__ w_time, const float* __restrict__ b_time,
    const float* __restrict__ g_time, const float* __restrict__ be_time,
    const _Float16* __restrict__ Wp, const float* __restrict__ bm,
    float* __restrict__ h, _Float16* __restrict__ P) {
  __shared__ _Float16 tile[64 * 168];  // stride 336 B = 84 dw (84%32=20 -> conflict-free-ish)
  const int t = threadIdx.x;
  const int lane = t & 63, w = t >> 6;
  const int mrow = lane & 15, quad = lane >> 4;
  const int n0 = blockIdx.x * 64;  // grid 1563
  int arow = n0 + w * 16 + mrow; if (arow > NN - 1) arow = NN - 1;
  const float* xrow = x + (size_t)arow * 128;
  floatx4 acc[8];
#pragma unroll
  for (int i = 0; i < 8; ++i) acc[i] = (floatx4)0.f;
  const _Float16* wbase = We + (size_t)mrow * 128 + quad * 8;
#pragma unroll
  for (int kt = 0; kt < 4; ++kt) {
    const int k0 = kt * 32 + quad * 8;
    float4 f0 = *(const float4*)&xrow[k0];
    float4 f1 = *(const float4*)&xrow[k0 + 4];
    half8 a = {(_Float16)f0.x, (_Float16)f0.y, (_Float16)f0.z, (_Float16)f0.w,
               (_Float16)f1.x, (_Float16)f1.y, (_Float16)f1.z, (_Float16)f1.w};
#pragma unroll
    for (int i = 0; i < 8; ++i) {
      half8 b = *(const half8*)&wbase[i * 16 * 128 + kt * 32];
      acc[i] = __builtin_amdgcn_mfma_f32_16x16x32_f16(a, b, acc[i], 0, 0, 0);
    }
  }
#pragma unroll
  for (int r = 0; r < 4; ++r) {
    const int row = quad * 4 + r;
    const int node = n0 + w * 16 + row;
    float v[8], s = 0.f, ss = 0.f;
#pragma unroll
    for (int i = 0; i < 8; ++i) {
      v[i] = acc[i][r] + b_enc[i * 16 + mrow];
      s += v[i]; ss = fmaf(v[i], v[i], ss);
    }
#pragma unroll
    for (int off = 1; off < 16; off <<= 1) { s += __shfl_xor(s, off); ss += __shfl_xor(ss, off); }
    const float m = s * (1.f / 128.f);
    const float var = ss * (1.f / 128.f) - m * m;
    const float rs = rsqrtf(var + 1e-5f);
#pragma unroll
    for (int i = 0; i < 8; ++i) {
      int j = i * 16 + mrow;
      float y = fmaxf(fmaf((v[i] - m) * rs, g_enc[j], be_enc[j]), 0.f);
      tile[(w * 16 + row) * 168 + j] = (_Float16)y;
      if (node < NN) h[(size_t)node * 160 + j] = y;
    }
  }
  // time dims 128..159 (closed-form LN); spans all 64 nodes -> barrier below
  float mw = 0.f, mb = 0.f;
  for (int d = 0; d < 32; ++d) { mw += w_time[d]; mb += b_time[d]; }
  mw *= (1.f / 32.f); mb *= (1.f / 32.f);
  float A = 0.f, B = 0.f, C = 0.f;
  for (int d = 0; d < 32; ++d) {
    float a = w_time[d] - mw, c = b_time[d] - mb;
    A = fmaf(a, a, A); B = fmaf(a, c, B); C = fmaf(c, c, C);
  }
  A *= (1.f / 32.f); B *= (1.f / 32.f); C *= (1.f / 32.f);
#pragma unroll
  for (int r2 = 0; r2 < 8; ++r2) {
    int q = t + r2 * 256;  // 2048 = 64 nodes x 32 dims
    int nn = q >> 5, d = q & 31;
    int node = n0 + nn;
    int nodec = (node > NN - 1) ? NN - 1 : node;
    float tsv = tsp[nodec];
    float mt = fmaf(mw, tsv, mb);
    float vart = fmaf(fmaf(A, tsv, 2.f * B), tsv, C);
    float rst = rsqrtf(vart + 1e-5f);
    float vv = fmaf(w_time[d], tsv, b_time[d]);
    float y = fmaxf(fmaf((vv - mt) * rst, g_time[d], be_time[d]), 0.f);
    tile[nn * 168 + 128 + d] = (_Float16)y;
    if (node < NN) h[(size_t)node * 160 + 128 + d] = y;
  }
  __syncthreads();
  // ---- phase 2: proj from LDS tile
  floatx4 acc2[20];
#pragma unroll
  for (int i = 0; i < 20; ++i) acc2[i] = (floatx4)0.f;
  const _Float16* wbase2 = Wp + (size_t)mrow * 160 + quad * 8;
#pragma unroll
  for (int kt = 0; kt < 5; ++kt) {
    half8 a = *(const half8*)&tile[(w * 16 + mrow) * 168 + kt * 32 + quad * 8];
#pragma unroll
    for (int i = 0; i < 20; ++i) {
      half8 b = *(const half8*)&wbase2[i * 16 * 160 + kt * 32];
      acc2[i] = __builtin_amdgcn_mfma_f32_16x16x32_f16(a, b, acc2[i], 0, 0, 0);
    }
  }
#pragma unroll
  for (int r = 0; r < 4; ++r) {
    const int row = quad * 4 + r;
    const int node = n0 + w * 16 + row;
    if (node < NN) {
      _Float16* prow = &P[(size_t)node * 320];
#pragma unroll
      for (int i = 0; i < 20; ++i) {
        int j2 = i * 16 + mrow;
        float v2 = acc2[i][r] + ((j2 >= 160) ? bm[j2 - 160] : 0.f);
        prow[j2] = (_Float16)v2;
      }
    }
  }
}

// ---------------------------------------------------------------- edge aggregate (CSR, 2-way unroll)
// 32-lane group per dst node; lane jg owns dims {4jg..4jg+3, 128+jg}; writes f16 mean.
__global__ __launch_bounds__(256) void k_edge3(
    const _Float16* __restrict__ P, const int* __restrict__ off,
    const int2* __restrict__ selist,
    const float* __restrict__ gm, const float* __restrict__ bem,
    _Float16* __restrict__ msum16) {
  const int t = threadIdx.x;
  const int jg = t & 31, g = t >> 5;
  const int n = blockIdx.x * 8 + g;  // grid exact: 12500*8 = 100000
  float gmv[5], bev[5], pdv[5];
#pragma unroll
  for (int i = 0; i < 4; ++i) { gmv[i] = gm[4 * jg + i]; bev[i] = bem[4 * jg + i]; }
  gmv[4] = gm[128 + jg]; bev[4] = bem[128 + jg];
  const _Float16* pd = P + (size_t)n * 320 + 160;
  half4 pdh = *(const half4*)&pd[4 * jg];
  pdv[0] = (float)pdh.x; pdv[1] = (float)pdh.y; pdv[2] = (float)pdh.z; pdv[3] = (float)pdh.w;
  pdv[4] = (float)pd[128 + jg];
  float acc[5] = {0.f, 0.f, 0.f, 0.f, 0.f};
  const int e0 = off[n], e1 = off[n + 1];
  int k = e0;
  for (; k + 1 < e1; k += 2) {  // two independent gather+LN chains in flight
    int2 seA = selist[k], seB = selist[k + 1];
    const _Float16* psA = P + (size_t)seA.x * 320;
    const _Float16* psB = P + (size_t)seB.x * 320;
    const float weA = __int_as_float(seA.y), weB = __int_as_float(seB.y);
    half4 a4 = *(const half4*)&psA[4 * jg];
    half4 b4 = *(const half4*)&psB[4 * jg];
    float a5 = (float)psA[128 + jg], b5 = (float)psB[128 + jg];
    float vA[5], vB[5];
    vA[0] = (float)a4.x + pdv[0]; vA[1] = (float)a4.y + pdv[1];
    vA[2] = (float)a4.z + pdv[2]; vA[3] = (float)a4.w + pdv[3]; vA[4] = a5 + pdv[4];
    vB[0] = (float)b4.x + pdv[0]; vB[1] = (float)b4.y + pdv[1];
    vB[2] = (float)b4.z + pdv[2]; vB[3] = (float)b4.w + pdv[3]; vB[4] = b5 + pdv[4];
    float sA = 0.f, ssA = 0.f, sB = 0.f, ssB = 0.f;
#pragma unroll
    for (int i = 0; i < 5; ++i) {
      sA += vA[i]; ssA = fmaf(vA[i], vA[i], ssA);
      sB += vB[i]; ssB = fmaf(vB[i], vB[i], ssB);
    }
#pragma unroll
    for (int o = 1; o < 32; o <<= 1) {
      sA += __shfl_xor(sA, o); ssA += __shfl_xor(ssA, o);
      sB += __shfl_xor(sB, o); ssB += __shfl_xor(ssB, o);
    }
    const float mA = sA * (1.f / 160.f), mB = sB * (1.f / 160.f);
    const float rsA = rsqrtf(ssA * (1.f / 160.f) - mA * mA + 1e-5f);
    const float rsB = rsqrtf(ssB * (1.f / 160.f) - mB * mB + 1e-5f);
#pragma unroll
    for (int i = 0; i < 5; ++i) {
      acc[i] = fmaf(fmaxf(fmaf((vA[i] - mA) * rsA, gmv[i], bev[i]), 0.f), weA, acc[i]);
      acc[i] = fmaf(fmaxf(fmaf((vB[i] - mB) * rsB, gmv[i], bev[i]), 0.f), weB, acc[i]);
    }
  }
  if (k < e1) {
    int2 se = selist[k];
    const _Float16* ps = P + (size_t)se.x * 320;
    const float we = __int_as_float(se.y);
    half4 s4 = *(const half4*)&ps[4 * jg];
    float v[5], s = 0.f, ss = 0.f;
    v[0] = (float)s4.x + pdv[0]; v[1] = (float)s4.y + pdv[1];
    v[2] = (float)s4.z + pdv[2]; v[3] = (float)s4.w + pdv[3];
    v[4] = (float)ps[128 + jg] + pdv[4];
#pragma unroll
    for (int i = 0; i < 5; ++i) { s += v[i]; ss = fmaf(v[i], v[i], ss); }
#pragma unroll
    for (int o = 1; o < 32; o <<= 1) { s += __shfl_xor(s, o); ss += __shfl_xor(ss, o); }
    const float m = s * (1.f / 160.f);
    const float rs = rsqrtf(ss * (1.f / 160.f) - m * m + 1e-5f);
#pragma unroll
    for (int i = 0; i < 5; ++i)
      acc[i] = fmaf(fmaxf(fmaf((v[i] - m) * rs, gmv[i], bev[i]), 0.f), we, acc[i]);
  }
  const float c = (float)(e1 - e0);
  const float ic = (c > 0.f) ? 1.f / (c + 1e-8f) : 0.f;
  _Float16* orow = msum16 + (size_t)n * 160;
  half4 o4 = {(_Float16)(acc[0] * ic), (_Float16)(acc[1] * ic),
              (_Float16)(acc[2] * ic), (_Float16)(acc[3] * ic)};
  *(half4*)&orow[4 * jg] = o4;
  orow[128 + jg] = (_Float16)(acc[4] * ic);
}

// ---------------------------------------------------------------- fused update + proj (next layer)
__global__ __launch_bounds__(256) void k_update_proj(
    float* __restrict__ h, const _Float16* __restrict__ msum16,
    const _Float16* __restrict__ Wu, const float* __restrict__ bu,
    const float* __restrict__ gu, const float* __restrict__ beu,
    const float* __restrict__ wg, const float* __restrict__ bg,
    const _Float16* __restrict__ Wp, const float* __restrict__ bm,
    _Float16* __restrict__ P) {
  __shared__ _Float16 tile[64 * 168];
  const int t = threadIdx.x;
  const int lane = t & 63, w = t >> 6;
  const int mrow = lane & 15, quad = lane >> 4;
  const int n0 = blockIdx.x * 64;  // grid 1563
  int arow = n0 + w * 16 + mrow; if (arow > NN - 1) arow = NN - 1;
  const float* hrowp = h + (size_t)arow * 160;
  const _Float16* mrowp = msum16 + (size_t)arow * 160;
  floatx4 acc[10];
#pragma unroll
  for (int i = 0; i < 10; ++i) acc[i] = (floatx4)0.f;
  const _Float16* wbase = Wu + (size_t)mrow * 320 + quad * 8;
  float gp = 0.f;
#pragma unroll
  for (int kt = 0; kt < 5; ++kt) {
    const int k0 = kt * 32 + quad * 8;
    float4 f0 = *(const float4*)&hrowp[k0];
    float4 f1 = *(const float4*)&hrowp[k0 + 4];
    float4 g0 = *(const float4*)&wg[k0];
    float4 g1 = *(const float4*)&wg[k0 + 4];
    gp = fmaf(f0.x, g0.x, gp); gp = fmaf(f0.y, g0.y, gp);
    gp = fmaf(f0.z, g0.z, gp); gp = fmaf(f0.w, g0.w, gp);
    gp = fmaf(f1.x, g1.x, gp); gp = fmaf(f1.y, g1.y, gp);
    gp = fmaf(f1.z, g1.z, gp); gp = fmaf(f1.w, g1.w, gp);
    half8 a = {(_Float16)f0.x, (_Float16)f0.y, (_Float16)f0.z, (_Float16)f0.w,
               (_Float16)f1.x, (_Float16)f1.y, (_Float16)f1.z, (_Float16)f1.w};
#pragma unroll
    for (int i = 0; i < 10; ++i) {
      half8 b = *(const half8*)&wbase[i * 16 * 320 + kt * 32];
      acc[i] = __builtin_amdgcn_mfma_f32_16x16x32_f16(a, b, acc[i], 0, 0, 0);
    }
  }
#pragma unroll
  for (int kt = 5; kt < 10; ++kt) {
    const int k0 = kt * 32 + quad * 8 - 160;
    half8 a = *(const half8*)&mrowp[k0];
#pragma unroll
    for (int i = 0; i < 10; ++i) {
      half8 b = *(const half8*)&wbase[i * 16 * 320 + kt * 32];
      acc[i] = __builtin_amdgcn_mfma_f32_16x16x32_f16(a, b, acc[i], 0, 0, 0);
    }
  }
  gp += __shfl_xor(gp, 16); gp += __shfl_xor(gp, 32);
  const float twv = 1.f / (1.f + expf(-(gp + bg[0])));
#pragma unroll
  for (int r = 0; r < 4; ++r) {
    const int row = quad * 4 + r;
    const int node = n0 + w * 16 + row;
    const int nodec = (node > NN - 1) ? NN - 1 : node;
    float v[10], s = 0.f, ss = 0.f;
#pragma unroll
    for (int i = 0; i < 10; ++i) {
      v[i] = acc[i][r] + bu[i * 16 + mrow];
      s += v[i]; ss = fmaf(v[i], v[i], ss);
    }
#pragma unroll
    for (int off = 1; off < 16; off <<= 1) { s += __shfl_xor(s, off); ss += __shfl_xor(ss, off); }
    const float m = s * (1.f / 160.f);
    const float var = ss * (1.f / 160.f) - m * m;
    const float rs = rsqrtf(var + 1e-5f);
    const float g = __shfl(twv, row);
    const float* hrow = &h[(size_t)nodec * 160];
#pragma unroll
    for (int i = 0; i < 10; ++i) {
      int j = i * 16 + mrow;
      float hnew = fmaxf(fmaf((v[i] - m) * rs, gu[j], beu[j]), 0.f);
      float hold = hrow[j];
      float hupd = fmaf(g, hnew - hold, hold);
      tile[(w * 16 + row) * 168 + j] = (_Float16)hupd;
      if (node < NN) h[(size_t)node * 160 + j] = hupd;
    }
  }
  __syncthreads();
  // ---- phase 2: proj from LDS tile
  floatx4 acc2[20];
#pragma unroll
  for (int i = 0; i < 20; ++i) acc2[i] = (floatx4)0.f;
  const _Float16* wbase2 = Wp + (size_t)mrow * 160 + quad * 8;
#pragma unroll
  for (int kt = 0; kt < 5; ++kt) {
    half8 a = *(const half8*)&tile[(w * 16 + mrow) * 168 + kt * 32 + quad * 8];
#pragma unroll
    for (int i = 0; i < 20; ++i) {
      half8 b = *(const half8*)&wbase2[i * 16 * 160 + kt * 32];
      acc2[i] = __builtin_amdgcn_mfma_f32_16x16x32_f16(a, b, acc2[i], 0, 0, 0);
    }
  }
#pragma unroll
  for (int r = 0; r < 4; ++r) {
    const int row = quad * 4 + r;
    const int node = n0 + w * 16 + row;
    if (node < NN) {
      _Float16* prow = &P[(size_t)node * 320];
#pragma unroll
      for (int i = 0; i < 20; ++i) {
        int j2 = i * 16 + mrow;
        float v2 = acc2[i][r] + ((j2 >= 160) ? bm[j2 - 160] : 0.f);
        prow[j2] = (_Float16)v2;
      }
    }
  }
}

// ---------------------------------------------------------------- fused update + output proj + L2 norm
__global__ __launch_bounds__(256) void k_update_out(
    const float* __restrict__ h, const _Float16* __restrict__ msum16,
    const _Float16* __restrict__ Wu, const float* __restrict__ bu,
    const float* __restrict__ gu, const float* __restrict__ beu,
    const float* __restrict__ wg, const float* __restrict__ bg,
    const _Float16* __restrict__ Wo, const float* __restrict__ b_out,
    float* __restrict__ out) {
  __shared__ _Float16 tile[64 * 168];
  const int t = threadIdx.x;
  const int lane = t & 63, w = t >> 6;
  const int mrow = lane & 15, quad = lane >> 4;
  const int n0 = blockIdx.x * 64;  // grid 1563
  int arow = n0 + w * 16 + mrow; if (arow > NN - 1) arow = NN - 1;
  const float* hrowp = h + (size_t)arow * 160;
  const _Float16* mrowp = msum16 + (size_t)arow * 160;
  floatx4 acc[10];
#pragma unroll
  for (int i = 0; i < 10; ++i) acc[i] = (floatx4)0.f;
  const _Float16* wbase = Wu + (size_t)mrow * 320 + quad * 8;
  float gp = 0.f;
#pragma unroll
  for (int kt = 0; kt < 5; ++kt) {
    const int k0 = kt * 32 + quad * 8;
    float4 f0 = *(const float4*)&hrowp[k0];
    float4 f1 = *(const float4*)&hrowp[k0 + 4];
    float4 g0 = *(const float4*)&wg[k0];
    float4 g1 = *(const float4*)&wg[k0 + 4];
    gp = fmaf(f0.x, g0.x, gp); gp = fmaf(f0.y, g0.y, gp);
    gp = fmaf(f0.z, g0.z, gp); gp = fmaf(f0.w, g0.w, gp);
    gp = fmaf(f1.x, g1.x, gp); gp = fmaf(f1.y, g1.y, gp);
    gp = fmaf(f1.z, g1.z, gp); gp = fmaf(f1.w, g1.w, gp);
    half8 a = {(_Float16)f0.x, (_Float16)f0.y, (_Float16)f0.z, (_Float16)f0.w,
               (_Float16)f1.x, (_Float16)f1.y, (_Float16)f1.z, (_Float16)f1.w};
#pragma unroll
    for (int i = 0; i < 10; ++i) {
      half8 b = *(const half8*)&wbase[i * 16 * 320 + kt * 32];
      acc[i] = __builtin_amdgcn_mfma_f32_16x16x32_f16(a, b, acc[i], 0, 0, 0);
    }
  }
#pragma unroll
  for (int kt = 5; kt < 10; ++kt) {
    const int k0 = kt * 32 + quad * 8 - 160;
    half8 a = *(const half8*)&mrowp[k0];
#pragma unroll
    for (int i = 0; i < 10; ++i) {
      half8 b = *(const half8*)&wbase[i * 16 * 320 + kt * 32];
      acc[i] = __builtin_amdgcn_mfma_f32_16x16x32_f16(a, b, acc[i], 0, 0, 0);
    }
  }
  gp += __shfl_xor(gp, 16); gp += __shfl_xor(gp, 32);
  const float twv = 1.f / (1.f + expf(-(gp + bg[0])));
#pragma unroll
  for (int r = 0; r < 4; ++r) {
    const int row = quad * 4 + r;
    const int node = n0 + w * 16 + row;
    const int nodec = (node > NN - 1) ? NN - 1 : node;
    float v[10], s = 0.f, ss = 0.f;
#pragma unroll
    for (int i = 0; i < 10; ++i) {
      v[i] = acc[i][r] + bu[i * 16 + mrow];
      s += v[i]; ss = fmaf(v[i], v[i], ss);
    }
#pragma unroll
    for (int off = 1; off < 16; off <<= 1) { s += __shfl_xor(s, off); ss += __shfl_xor(ss, off); }
    const float m = s * (1.f / 160.f);
    const float var = ss * (1.f / 160.f) - m * m;
    const float rs = rsqrtf(var + 1e-5f);
    const float g = __shfl(twv, row);
    const float* hrow = &h[(size_t)nodec * 160];
#pragma unroll
    for (int i = 0; i < 10; ++i) {
      int j = i * 16 + mrow;
      float hnew = fmaxf(fmaf((v[i] - m) * rs, gu[j], beu[j]), 0.f);
      float hold = hrow[j];
      float hupd = fmaf(g, hnew - hold, hold);  // final h: LDS only (dead after this kernel)
      tile[(w * 16 + row) * 168 + j] = (_Float16)hupd;
    }
  }
  __syncthreads();
  // ---- phase 2: output projection + L2 normalize
  floatx4 acc2[8];
#pragma unroll
  for (int i = 0; i < 8; ++i) acc2[i] = (floatx4)0.f;
  const _Float16* wbase2 = Wo + (size_t)mrow * 160 + quad * 8;
#pragma unroll
  for (int kt = 0; kt < 5; ++kt) {
    half8 a = *(const half8*)&tile[(w * 16 + mrow) * 168 + kt * 32 + quad * 8];
#pragma unroll
    for (int i = 0; i < 8; ++i) {
      half8 b = *(const half8*)&wbase2[i * 16 * 160 + kt * 32];
      acc2[i] = __builtin_amdgcn_mfma_f32_16x16x32_f16(a, b, acc2[i], 0, 0, 0);
    }
  }
#pragma unroll
  for (int r = 0; r < 4; ++r) {
    const int row = quad * 4 + r;
    const int node = n0 + w * 16 + row;
    float v[8], ss = 0.f;
#pragma unroll
    for (int i = 0; i < 8; ++i) {
      v[i] = acc2[i][r] + b_out[i * 16 + mrow];
      ss = fmaf(v[i], v[i], ss);
    }
#pragma unroll
    for (int off = 1; off < 16; off <<= 1) ss += __shfl_xor(ss, off);
    const float inv = 1.f / fmaxf(sqrtf(ss), 1e-12f);
    if (node < NN) {
#pragma unroll
      for (int i = 0; i < 8; ++i)
        out[(size_t)node * 128 + i * 16 + mrow] = v[i] * inv;
    }
  }
}

// ---------------------------------------------------------------- launch
extern "C" void kernel_launch(void* const* d_in, const int* in_sizes, int n_in,
                              void* d_out, int out_size, void* d_ws, size_t ws_size,
                              hipStream_t stream) {
  (void)in_sizes; (void)n_in; (void)out_size; (void)ws_size;
  const float* x       = (const float*)d_in[0];
  const int*   ei      = (const int*)  d_in[1];
  const float* ew      = (const float*)d_in[2];
  const float* tsp     = (const float*)d_in[3];
  const float* w_enc   = (const float*)d_in[4];
  const float* b_enc   = (const float*)d_in[5];
  const float* g_enc   = (const float*)d_in[6];
  const float* be_enc  = (const float*)d_in[7];
  const float* w_time  = (const float*)d_in[8];
  const float* b_time  = (const float*)d_in[9];
  const float* g_time  = (const float*)d_in[10];
  const float* be_time = (const float*)d_in[11];
  const float* wm      = (const float*)d_in[12];
  const float* bm      = (const float*)d_in[13];
  const float* gm      = (const float*)d_in[14];
  const float* bem     = (const float*)d_in[15];
  const float* wu      = (const float*)d_in[16];
  const float* bu      = (const float*)d_in[17];
  const float* gu      = (const float*)d_in[18];
  const float* beu     = (const float*)d_in[19];
  const float* wg      = (const float*)d_in[20];
  const float* bg      = (const float*)d_in[21];
  const float* w_out   = (const float*)d_in[22];
  const float* b_out   = (const float*)d_in[23];
  float* out = (float*)d_out;

  // ws layout (bytes): h f32[NN*160] @0 (64M) | msum16 f16[NN*160] @64,000,000 (32M)
  //   P f16[NN*320] @96,000,000 (64M) | Wu16 @160,000,000 (204,800) | Wo16 @160,204,800 (40,960)
  //   total 160,245,760 (< 192,440,960 used in passing round 2)
  char* ws = (char*)d_ws;
  float* h          = (float*)ws;
  _Float16* msum16  = (_Float16*)(ws + 64000000);
  _Float16* P       = (_Float16*)(ws + 96000000);
  _Float16* Wu16    = (_Float16*)(ws + 160000000);
  _Float16* Wo16    = (_Float16*)(ws + 160204800);
  // d_out doubles as scratch; all of it is only READ before k_update_out writes out.
  // (k_update_out reads no d_out-resident scratch: Wu16/Wo16 live in ws.)
  char* ob = (char*)d_out;
  _Float16* Wp16 = (_Float16*)ob;             // 204,800
  _Float16* We16 = (_Float16*)(ob + 204800);  // 32,768
  int* off    = (int*)(ob + 237568);          // 400,016
  int* cnti   = (int*)(ob + 637584);          // 400,000
  int* cursor = (int*)(ob + 1037584);         // 400,000
  int* bsum   = (int*)(ob + 1437584);         // 1,568
  int* bsum2  = (int*)(ob + 1439152);         // 1,568
  int2* selist = (int2*)(ob + 1440720);       // 6,400,000 -> 7,840,720 < 51,200,000

  // weight prep + CSR build (edges static across layers: build once)
  k_zero<<<dim3(98), dim3(256), 0, stream>>>((float4*)cnti, 25000);
  k_cast<<<dim3(400), dim3(256), 0, stream>>>(wu, Wu16, 102400);
  k_cast<<<dim3(64),  dim3(256), 0, stream>>>(w_enc, We16, 16384);
  k_cast<<<dim3(80),  dim3(256), 0, stream>>>(w_out, Wo16, 20480);
  k_prep_wm<<<dim3(400), dim3(256), 0, stream>>>(wm, Wp16);
  k_count_i<<<dim3(3125), dim3(256), 0, stream>>>(ei, cnti);
  k_scan1<<<dim3(391), dim3(256), 0, stream>>>(cnti, off, bsum);
  k_scan2<<<dim3(1), dim3(512), 0, stream>>>(bsum, bsum2);
  k_scan3<<<dim3(391), dim3(256), 0, stream>>>(off, bsum2, cursor);
  k_scatter<<<dim3(3125), dim3(256), 0, stream>>>(ei, ew, cursor, selist);

  k_encode_proj<<<dim3(1563), dim3(256), 0, stream>>>(
      x, tsp, We16, b_enc, g_enc, be_enc, w_time, b_time, g_time, be_time,
      Wp16, bm, h, P);
  k_edge3<<<dim3(12500), dim3(256), 0, stream>>>(P, off, selist, gm, bem, msum16);
  k_update_proj<<<dim3(1563), dim3(256), 0, stream>>>(
      h, msum16, Wu16, bu, gu, beu, wg, bg,
      Wp16 + 51200, bm + 160, P);
  k_edge3<<<dim3(12500), dim3(256), 0, stream>>>(P, off, selist, gm + 160, bem + 160, msum16);
  k_update_out<<<dim3(1563), dim3(256), 0, stream>>>(
      h, msum16, Wu16 + 51200, bu + 160, gu + 160, beu + 160, wg + 160, bg + 1,
      Wo16, b_out, out);
}

// Round 7
// 676.042 us; speedup vs baseline: 9.8202x; 1.1842x over previous
//
#include <hip/hip_runtime.h>

#define NN 100000
#define NE 800000
// D = 160, 2D = 320, F = 128

typedef _Float16 half8 __attribute__((ext_vector_type(8)));
typedef _Float16 half4 __attribute__((ext_vector_type(4)));
typedef float floatx4 __attribute__((ext_vector_type(4)));

// ---------------------------------------------------------------- zero
__global__ __launch_bounds__(256) void k_zero(float4* __restrict__ p, int n4) {
  int i = blockIdx.x * 256 + threadIdx.x;
  if (i < n4) p[i] = make_float4(0.f, 0.f, 0.f, 0.f);
}

// ---------------------------------------------------------------- weight casts
__global__ __launch_bounds__(256) void k_cast(const float* __restrict__ s,
                                              _Float16* __restrict__ d, int n) {
  int i = blockIdx.x * 256 + threadIdx.x;
  if (i < n) d[i] = (_Float16)s[i];
}
// Wp[l][j2][k] (j2<160: wm[l][j2][k], else wm[l][j2-160][160+k]); total 2*320*160
__global__ __launch_bounds__(256) void k_prep_wm(const float* __restrict__ wm,
                                                 _Float16* __restrict__ Wp) {
  int i = blockIdx.x * 256 + threadIdx.x;
  if (i >= 102400) return;
  int l = i / 51200, rem = i - l * 51200;
  int j2 = rem / 160, k = rem - j2 * 160;
  float v = (j2 < 160) ? wm[l * 51200 + j2 * 320 + k]
                       : wm[l * 51200 + (j2 - 160) * 320 + 160 + k];
  Wp[i] = (_Float16)v;
}

// ---------------------------------------------------------------- CSR build
__global__ __launch_bounds__(256) void k_count_i(const int* __restrict__ ei,
                                                 int* __restrict__ cnti) {
  int e = blockIdx.x * 256 + threadIdx.x;  // grid exact: 3125*256 = 800000
  atomicAdd(&cnti[ei[NE + e]], 1);
}

__global__ __launch_bounds__(256) void k_scan1(const int* __restrict__ cnti,
                                               int* __restrict__ off,
                                               int* __restrict__ bsum) {
  __shared__ int sh[256];
  const int t = threadIdx.x;
  const int i = blockIdx.x * 256 + t;  // grid 391 covers 100096
  int v = (i < NN) ? cnti[i] : 0;
  sh[t] = v;
  __syncthreads();
  for (int d = 1; d < 256; d <<= 1) {
    int add = (t >= d) ? sh[t - d] : 0;
    __syncthreads();
    sh[t] += add;
    __syncthreads();
  }
  if (i < NN) off[i] = sh[t] - v;
  if (t == 255) bsum[blockIdx.x] = sh[255];
}

__global__ __launch_bounds__(512) void k_scan2(const int* __restrict__ bsum,
                                               int* __restrict__ bsum2) {
  __shared__ int sh[512];
  const int t = threadIdx.x;
  int v = (t < 391) ? bsum[t] : 0;
  sh[t] = v;
  __syncthreads();
  for (int d = 1; d < 512; d <<= 1) {
    int add = (t >= d) ? sh[t - d] : 0;
    __syncthreads();
    sh[t] += add;
    __syncthreads();
  }
  if (t < 391) bsum2[t] = sh[t] - v;
}

__global__ __launch_bounds__(256) void k_scan3(int* __restrict__ off,
                                               const int* __restrict__ bsum2,
                                               int* __restrict__ cursor) {
  const int i = blockIdx.x * 256 + threadIdx.x;
  if (i < NN) {
    int o = off[i] + bsum2[blockIdx.x];
    off[i] = o;
    cursor[i] = o;
  }
  if (i == 0) off[NN] = NE;
}

__global__ __launch_bounds__(256) void k_scatter(const int* __restrict__ ei,
                                                 const float* __restrict__ ew,
                                                 int* __restrict__ cursor,
                                                 int2* __restrict__ selist) {
  int e = blockIdx.x * 256 + threadIdx.x;  // grid exact 3125
  int dst = ei[NE + e];
  int pos = atomicAdd(&cursor[dst], 1);
  selist[pos] = make_int2(ei[e], __float_as_int(ew[e]));
}

// ---------------------------------------------------------------- B-panel staging
// Stage nj rows x kw halfs (K-contiguous) of W (row stride SR) into Bsh (row
// stride 72 halfs -> uniform 8-phase bank pattern for b128 reads).
__device__ __forceinline__ void stage_B(_Float16* Bsh, const _Float16* W, int SR,
                                        int k0, int nj, int kw, int t) {
  const int pc = kw >> 3;          // 16-B pieces per row
  const int chunks = nj * pc;
  for (int c = t; c < chunks; c += 256) {
    int j = c / pc, piece = c - j * pc;
    *(half8*)&Bsh[j * 72 + piece * 8] = *(const half8*)&W[(size_t)j * SR + k0 + piece * 8];
  }
}

// ---------------------------------------------------------------- fused encoder + proj
__global__ __launch_bounds__(256) void k_encode_proj(
    const float* __restrict__ x, const float* __restrict__ tsp,
    const _Float16* __restrict__ We,
    const float* __restrict__ b_enc, const float* __restrict__ g_enc,
    const float* __restrict__ be_enc,
    const float* __restrict__ w_time, const float* __restrict__ b_time,
    const float* __restrict__ g_time, const float* __restrict__ be_time,
    const _Float16* __restrict__ Wp, const float* __restrict__ bm,
    _Float16* __restrict__ h16, _Float16* __restrict__ P) {
  __shared__ _Float16 tile[64 * 168];
  __shared__ _Float16 Bsh[160 * 72];
  const int t = threadIdx.x;
  const int lane = t & 63, w = t >> 6;
  const int mrow = lane & 15, quad = lane >> 4;
  const int n0 = blockIdx.x * 64;  // grid 1563
  int arow = n0 + w * 16 + mrow; if (arow > NN - 1) arow = NN - 1;
  const float* xrow = x + (size_t)arow * 128;
  // hoist all A fragments (f32 -> f16)
  half8 areg[4];
#pragma unroll
  for (int kt = 0; kt < 4; ++kt) {
    const int k0 = kt * 32 + quad * 8;
    float4 f0 = *(const float4*)&xrow[k0];
    float4 f1 = *(const float4*)&xrow[k0 + 4];
    half8 a = {(_Float16)f0.x, (_Float16)f0.y, (_Float16)f0.z, (_Float16)f0.w,
               (_Float16)f1.x, (_Float16)f1.y, (_Float16)f1.z, (_Float16)f1.w};
    areg[kt] = a;
  }
  floatx4 acc[8];
#pragma unroll
  for (int i = 0; i < 8; ++i) acc[i] = (floatx4)0.f;
  for (int ks = 0; ks < 2; ++ks) {  // K = 128 in 64-slices
    if (ks) __syncthreads();
    stage_B(Bsh, We, 128, ks * 64, 128, 64, t);
    __syncthreads();
#pragma unroll
    for (int h2 = 0; h2 < 2; ++h2) {
      half8 a = areg[ks * 2 + h2];
#pragma unroll
      for (int i = 0; i < 8; ++i) {
        half8 b = *(const half8*)&Bsh[(i * 16 + mrow) * 72 + h2 * 32 + quad * 8];
        acc[i] = __builtin_amdgcn_mfma_f32_16x16x32_f16(a, b, acc[i], 0, 0, 0);
      }
    }
  }
  // epilogue: LN(128) + relu -> tile + h16
#pragma unroll
  for (int r = 0; r < 4; ++r) {
    const int row = quad * 4 + r;
    const int node = n0 + w * 16 + row;
    float v[8], s = 0.f, ss = 0.f;
#pragma unroll
    for (int i = 0; i < 8; ++i) {
      v[i] = acc[i][r] + b_enc[i * 16 + mrow];
      s += v[i]; ss = fmaf(v[i], v[i], ss);
    }
#pragma unroll
    for (int off = 1; off < 16; off <<= 1) { s += __shfl_xor(s, off); ss += __shfl_xor(ss, off); }
    const float m = s * (1.f / 128.f);
    const float rs = rsqrtf(ss * (1.f / 128.f) - m * m + 1e-5f);
#pragma unroll
    for (int i = 0; i < 8; ++i) {
      int j = i * 16 + mrow;
      float y = fmaxf(fmaf((v[i] - m) * rs, g_enc[j], be_enc[j]), 0.f);
      tile[(w * 16 + row) * 168 + j] = (_Float16)y;
      if (node < NN) h16[(size_t)node * 160 + j] = (_Float16)y;
    }
  }
  // time dims 128..159 (closed-form LN)
  float mw = 0.f, mb = 0.f;
  for (int d = 0; d < 32; ++d) { mw += w_time[d]; mb += b_time[d]; }
  mw *= (1.f / 32.f); mb *= (1.f / 32.f);
  float A = 0.f, B = 0.f, C = 0.f;
  for (int d = 0; d < 32; ++d) {
    float a = w_time[d] - mw, c = b_time[d] - mb;
    A = fmaf(a, a, A); B = fmaf(a, c, B); C = fmaf(c, c, C);
  }
  A *= (1.f / 32.f); B *= (1.f / 32.f); C *= (1.f / 32.f);
#pragma unroll
  for (int r2 = 0; r2 < 8; ++r2) {
    int q = t + r2 * 256;  // 2048 = 64 nodes x 32 dims
    int nn = q >> 5, d = q & 31;
    int node = n0 + nn;
    int nodec = (node > NN - 1) ? NN - 1 : node;
    float tsv = tsp[nodec];
    float mt = fmaf(mw, tsv, mb);
    float rst = rsqrtf(fmaf(fmaf(A, tsv, 2.f * B), tsv, C) + 1e-5f);
    float vv = fmaf(w_time[d], tsv, b_time[d]);
    float y = fmaxf(fmaf((vv - mt) * rst, g_time[d], be_time[d]), 0.f);
    tile[nn * 168 + 128 + d] = (_Float16)y;
    if (node < NN) h16[(size_t)node * 160 + 128 + d] = (_Float16)y;
  }
  // ---- phase 2: P = tile @ Wp^T, 2 col-halves of 160
#pragma unroll 1
  for (int half_ = 0; half_ < 2; ++half_) {
    floatx4 acc2[10];
#pragma unroll
    for (int i = 0; i < 10; ++i) acc2[i] = (floatx4)0.f;
    const _Float16* Wh = Wp + (size_t)half_ * 160 * 160;
    int kbase = 0;
#pragma unroll 1
    for (int ks = 0; ks < 3; ++ks) {
      const int kw = (ks == 2) ? 32 : 64;
      __syncthreads();
      stage_B(Bsh, Wh, 160, kbase, 160, kw, t);
      __syncthreads();
      const int nkt = kw >> 5;
      for (int h2 = 0; h2 < nkt; ++h2) {
        half8 a = *(const half8*)&tile[(w * 16 + mrow) * 168 + kbase + h2 * 32 + quad * 8];
#pragma unroll
        for (int i = 0; i < 10; ++i) {
          half8 b = *(const half8*)&Bsh[(i * 16 + mrow) * 72 + h2 * 32 + quad * 8];
          acc2[i] = __builtin_amdgcn_mfma_f32_16x16x32_f16(a, b, acc2[i], 0, 0, 0);
        }
      }
      kbase += kw;
    }
#pragma unroll
    for (int r = 0; r < 4; ++r) {
      const int row = quad * 4 + r;
      const int node = n0 + w * 16 + row;
      if (node < NN) {
        _Float16* prow = &P[(size_t)node * 320 + half_ * 160];
#pragma unroll
        for (int i = 0; i < 10; ++i) {
          int jj = i * 16 + mrow;
          float v2 = acc2[i][r] + (half_ ? bm[jj] : 0.f);
          prow[jj] = (_Float16)v2;
        }
      }
    }
  }
}

// ---------------------------------------------------------------- edge aggregate (CSR, 2-way unroll)
__global__ __launch_bounds__(256) void k_edge3(
    const _Float16* __restrict__ P, const int* __restrict__ off,
    const int2* __restrict__ selist,
    const float* __restrict__ gm, const float* __restrict__ bem,
    _Float16* __restrict__ msum16) {
  const int t = threadIdx.x;
  const int jg = t & 31, g = t >> 5;
  const int n = blockIdx.x * 8 + g;  // grid exact: 12500*8 = 100000
  float gmv[5], bev[5], pdv[5];
#pragma unroll
  for (int i = 0; i < 4; ++i) { gmv[i] = gm[4 * jg + i]; bev[i] = bem[4 * jg + i]; }
  gmv[4] = gm[128 + jg]; bev[4] = bem[128 + jg];
  const _Float16* pd = P + (size_t)n * 320 + 160;
  half4 pdh = *(const half4*)&pd[4 * jg];
  pdv[0] = (float)pdh.x; pdv[1] = (float)pdh.y; pdv[2] = (float)pdh.z; pdv[3] = (float)pdh.w;
  pdv[4] = (float)pd[128 + jg];
  float acc[5] = {0.f, 0.f, 0.f, 0.f, 0.f};
  const int e0 = off[n], e1 = off[n + 1];
  int k = e0;
  for (; k + 1 < e1; k += 2) {
    int2 seA = selist[k], seB = selist[k + 1];
    const _Float16* psA = P + (size_t)seA.x * 320;
    const _Float16* psB = P + (size_t)seB.x * 320;
    const float weA = __int_as_float(seA.y), weB = __int_as_float(seB.y);
    half4 a4 = *(const half4*)&psA[4 * jg];
    half4 b4 = *(const half4*)&psB[4 * jg];
    float a5 = (float)psA[128 + jg], b5 = (float)psB[128 + jg];
    float vA[5], vB[5];
    vA[0] = (float)a4.x + pdv[0]; vA[1] = (float)a4.y + pdv[1];
    vA[2] = (float)a4.z + pdv[2]; vA[3] = (float)a4.w + pdv[3]; vA[4] = a5 + pdv[4];
    vB[0] = (float)b4.x + pdv[0]; vB[1] = (float)b4.y + pdv[1];
    vB[2] = (float)b4.z + pdv[2]; vB[3] = (float)b4.w + pdv[3]; vB[4] = b5 + pdv[4];
    float sA = 0.f, ssA = 0.f, sB = 0.f, ssB = 0.f;
#pragma unroll
    for (int i = 0; i < 5; ++i) {
      sA += vA[i]; ssA = fmaf(vA[i], vA[i], ssA);
      sB += vB[i]; ssB = fmaf(vB[i], vB[i], ssB);
    }
#pragma unroll
    for (int o = 1; o < 32; o <<= 1) {
      sA += __shfl_xor(sA, o); ssA += __shfl_xor(ssA, o);
      sB += __shfl_xor(sB, o); ssB += __shfl_xor(ssB, o);
    }
    const float mA = sA * (1.f / 160.f), mB = sB * (1.f / 160.f);
    const float rsA = rsqrtf(ssA * (1.f / 160.f) - mA * mA + 1e-5f);
    const float rsB = rsqrtf(ssB * (1.f / 160.f) - mB * mB + 1e-5f);
#pragma unroll
    for (int i = 0; i < 5; ++i) {
      acc[i] = fmaf(fmaxf(fmaf((vA[i] - mA) * rsA, gmv[i], bev[i]), 0.f), weA, acc[i]);
      acc[i] = fmaf(fmaxf(fmaf((vB[i] - mB) * rsB, gmv[i], bev[i]), 0.f), weB, acc[i]);
    }
  }
  if (k < e1) {
    int2 se = selist[k];
    const _Float16* ps = P + (size_t)se.x * 320;
    const float we = __int_as_float(se.y);
    half4 s4 = *(const half4*)&ps[4 * jg];
    float v[5], s = 0.f, ss = 0.f;
    v[0] = (float)s4.x + pdv[0]; v[1] = (float)s4.y + pdv[1];
    v[2] = (float)s4.z + pdv[2]; v[3] = (float)s4.w + pdv[3];
    v[4] = (float)ps[128 + jg] + pdv[4];
#pragma unroll
    for (int i = 0; i < 5; ++i) { s += v[i]; ss = fmaf(v[i], v[i], ss); }
#pragma unroll
    for (int o = 1; o < 32; o <<= 1) { s += __shfl_xor(s, o); ss += __shfl_xor(ss, o); }
    const float m = s * (1.f / 160.f);
    const float rs = rsqrtf(ss * (1.f / 160.f) - m * m + 1e-5f);
#pragma unroll
    for (int i = 0; i < 5; ++i)
      acc[i] = fmaf(fmaxf(fmaf((v[i] - m) * rs, gmv[i], bev[i]), 0.f), we, acc[i]);
  }
  const float c = (float)(e1 - e0);
  const float ic = (c > 0.f) ? 1.f / (c + 1e-8f) : 0.f;
  _Float16* orow = msum16 + (size_t)n * 160;
  half4 o4 = {(_Float16)(acc[0] * ic), (_Float16)(acc[1] * ic),
              (_Float16)(acc[2] * ic), (_Float16)(acc[3] * ic)};
  *(half4*)&orow[4 * jg] = o4;
  orow[128 + jg] = (_Float16)(acc[4] * ic);
}

// ---------------------------------------------------------------- fused update + proj (next layer)
__global__ __launch_bounds__(256) void k_update_proj(
    _Float16* __restrict__ h16, const _Float16* __restrict__ msum16,
    const _Float16* __restrict__ Wu, const float* __restrict__ bu,
    const float* __restrict__ gu, const float* __restrict__ beu,
    const float* __restrict__ wg, const float* __restrict__ bg,
    const _Float16* __restrict__ Wp, const float* __restrict__ bm,
    _Float16* __restrict__ P) {
  __shared__ _Float16 tile[64 * 168];
  __shared__ _Float16 Bsh[160 * 72];
  const int t = threadIdx.x;
  const int lane = t & 63, w = t >> 6;
  const int mrow = lane & 15, quad = lane >> 4;
  const int n0 = blockIdx.x * 64;  // grid 1563
  int arow = n0 + w * 16 + mrow; if (arow > NN - 1) arow = NN - 1;
  const _Float16* hrowp = h16 + (size_t)arow * 160;
  const _Float16* mrowp = msum16 + (size_t)arow * 160;
  // hoist A fragments
  half8 areg[10];
#pragma unroll
  for (int kt = 0; kt < 5; ++kt) areg[kt] = *(const half8*)&hrowp[kt * 32 + quad * 8];
#pragma unroll
  for (int kt = 5; kt < 10; ++kt) areg[kt] = *(const half8*)&mrowp[kt * 32 + quad * 8 - 160];
  // gate dot from hoisted h-fragments
  float gp = 0.f;
#pragma unroll
  for (int kt = 0; kt < 5; ++kt) {
    const int k0 = kt * 32 + quad * 8;
    float4 g0 = *(const float4*)&wg[k0];
    float4 g1 = *(const float4*)&wg[k0 + 4];
    gp = fmaf((float)areg[kt][0], g0.x, gp); gp = fmaf((float)areg[kt][1], g0.y, gp);
    gp = fmaf((float)areg[kt][2], g0.z, gp); gp = fmaf((float)areg[kt][3], g0.w, gp);
    gp = fmaf((float)areg[kt][4], g1.x, gp); gp = fmaf((float)areg[kt][5], g1.y, gp);
    gp = fmaf((float)areg[kt][6], g1.z, gp); gp = fmaf((float)areg[kt][7], g1.w, gp);
  }
  gp += __shfl_xor(gp, 16); gp += __shfl_xor(gp, 32);
  const float twv = 1.f / (1.f + expf(-(gp + bg[0])));
  floatx4 acc[10];
#pragma unroll
  for (int i = 0; i < 10; ++i) acc[i] = (floatx4)0.f;
  for (int ks = 0; ks < 5; ++ks) {  // K = 320 in 64-slices
    if (ks) __syncthreads();
    stage_B(Bsh, Wu, 320, ks * 64, 160, 64, t);
    __syncthreads();
#pragma unroll
    for (int h2 = 0; h2 < 2; ++h2) {
      half8 a = areg[ks * 2 + h2];
#pragma unroll
      for (int i = 0; i < 10; ++i) {
        half8 b = *(const half8*)&Bsh[(i * 16 + mrow) * 72 + h2 * 32 + quad * 8];
        acc[i] = __builtin_amdgcn_mfma_f32_16x16x32_f16(a, b, acc[i], 0, 0, 0);
      }
    }
  }
  // epilogue: LN + relu + gate blend -> tile + h16
#pragma unroll
  for (int r = 0; r < 4; ++r) {
    const int row = quad * 4 + r;
    const int node = n0 + w * 16 + row;
    const int nodec = (node > NN - 1) ? NN - 1 : node;
    float v[10], s = 0.f, ss = 0.f;
#pragma unroll
    for (int i = 0; i < 10; ++i) {
      v[i] = acc[i][r] + bu[i * 16 + mrow];
      s += v[i]; ss = fmaf(v[i], v[i], ss);
    }
#pragma unroll
    for (int off = 1; off < 16; off <<= 1) { s += __shfl_xor(s, off); ss += __shfl_xor(ss, off); }
    const float m = s * (1.f / 160.f);
    const float rs = rsqrtf(ss * (1.f / 160.f) - m * m + 1e-5f);
    const float g = __shfl(twv, row);
    const _Float16* hr = h16 + (size_t)nodec * 160;
#pragma unroll
    for (int i = 0; i < 10; ++i) {
      int j = i * 16 + mrow;
      float hnew = fmaxf(fmaf((v[i] - m) * rs, gu[j], beu[j]), 0.f);
      float hold = (float)hr[j];
      float hupd = fmaf(g, hnew - hold, hold);
      tile[(w * 16 + row) * 168 + j] = (_Float16)hupd;
      if (node < NN) h16[(size_t)node * 160 + j] = (_Float16)hupd;
    }
  }
  // ---- phase 2: P = tile @ Wp^T, 2 col-halves of 160
#pragma unroll 1
  for (int half_ = 0; half_ < 2; ++half_) {
    floatx4 acc2[10];
#pragma unroll
    for (int i = 0; i < 10; ++i) acc2[i] = (floatx4)0.f;
    const _Float16* Wh = Wp + (size_t)half_ * 160 * 160;
    int kbase = 0;
#pragma unroll 1
    for (int ks = 0; ks < 3; ++ks) {
      const int kw = (ks == 2) ? 32 : 64;
      __syncthreads();
      stage_B(Bsh, Wh, 160, kbase, 160, kw, t);
      __syncthreads();
      const int nkt = kw >> 5;
      for (int h2 = 0; h2 < nkt; ++h2) {
        half8 a = *(const half8*)&tile[(w * 16 + mrow) * 168 + kbase + h2 * 32 + quad * 8];
#pragma unroll
        for (int i = 0; i < 10; ++i) {
          half8 b = *(const half8*)&Bsh[(i * 16 + mrow) * 72 + h2 * 32 + quad * 8];
          acc2[i] = __builtin_amdgcn_mfma_f32_16x16x32_f16(a, b, acc2[i], 0, 0, 0);
        }
      }
      kbase += kw;
    }
#pragma unroll
    for (int r = 0; r < 4; ++r) {
      const int row = quad * 4 + r;
      const int node = n0 + w * 16 + row;
      if (node < NN) {
        _Float16* prow = &P[(size_t)node * 320 + half_ * 160];
#pragma unroll
        for (int i = 0; i < 10; ++i) {
          int jj = i * 16 + mrow;
          float v2 = acc2[i][r] + (half_ ? bm[jj] : 0.f);
          prow[jj] = (_Float16)v2;
        }
      }
    }
  }
}

// ---------------------------------------------------------------- fused update + output proj + L2 norm
__global__ __launch_bounds__(256) void k_update_out(
    const _Float16* __restrict__ h16, const _Float16* __restrict__ msum16,
    const _Float16* __restrict__ Wu, const float* __restrict__ bu,
    const float* __restrict__ gu, const float* __restrict__ beu,
    const float* __restrict__ wg, const float* __restrict__ bg,
    const _Float16* __restrict__ Wo, const float* __restrict__ b_out,
    float* __restrict__ out) {
  __shared__ _Float16 tile[64 * 168];
  __shared__ _Float16 Bsh[160 * 72];
  const int t = threadIdx.x;
  const int lane = t & 63, w = t >> 6;
  const int mrow = lane & 15, quad = lane >> 4;
  const int n0 = blockIdx.x * 64;  // grid 1563
  int arow = n0 + w * 16 + mrow; if (arow > NN - 1) arow = NN - 1;
  const _Float16* hrowp = h16 + (size_t)arow * 160;
  const _Float16* mrowp = msum16 + (size_t)arow * 160;
  half8 areg[10];
#pragma unroll
  for (int kt = 0; kt < 5; ++kt) areg[kt] = *(const half8*)&hrowp[kt * 32 + quad * 8];
#pragma unroll
  for (int kt = 5; kt < 10; ++kt) areg[kt] = *(const half8*)&mrowp[kt * 32 + quad * 8 - 160];
  float gp = 0.f;
#pragma unroll
  for (int kt = 0; kt < 5; ++kt) {
    const int k0 = kt * 32 + quad * 8;
    float4 g0 = *(const float4*)&wg[k0];
    float4 g1 = *(const float4*)&wg[k0 + 4];
    gp = fmaf((float)areg[kt][0], g0.x, gp); gp = fmaf((float)areg[kt][1], g0.y, gp);
    gp = fmaf((float)areg[kt][2], g0.z, gp); gp = fmaf((float)areg[kt][3], g0.w, gp);
    gp = fmaf((float)areg[kt][4], g1.x, gp); gp = fmaf((float)areg[kt][5], g1.y, gp);
    gp = fmaf((float)areg[kt][6], g1.z, gp); gp = fmaf((float)areg[kt][7], g1.w, gp);
  }
  gp += __shfl_xor(gp, 16); gp += __shfl_xor(gp, 32);
  const float twv = 1.f / (1.f + expf(-(gp + bg[0])));
  floatx4 acc[10];
#pragma unroll
  for (int i = 0; i < 10; ++i) acc[i] = (floatx4)0.f;
  for (int ks = 0; ks < 5; ++ks) {
    if (ks) __syncthreads();
    stage_B(Bsh, Wu, 320, ks * 64, 160, 64, t);
    __syncthreads();
#pragma unroll
    for (int h2 = 0; h2 < 2; ++h2) {
      half8 a = areg[ks * 2 + h2];
#pragma unroll
      for (int i = 0; i < 10; ++i) {
        half8 b = *(const half8*)&Bsh[(i * 16 + mrow) * 72 + h2 * 32 + quad * 8];
        acc[i] = __builtin_amdgcn_mfma_f32_16x16x32_f16(a, b, acc[i], 0, 0, 0);
      }
    }
  }
#pragma unroll
  for (int r = 0; r < 4; ++r) {
    const int row = quad * 4 + r;
    const int node = n0 + w * 16 + row;
    const int nodec = (node > NN - 1) ? NN - 1 : node;
    float v[10], s = 0.f, ss = 0.f;
#pragma unroll
    for (int i = 0; i < 10; ++i) {
      v[i] = acc[i][r] + bu[i * 16 + mrow];
      s += v[i]; ss = fmaf(v[i], v[i], ss);
    }
#pragma unroll
    for (int off = 1; off < 16; off <<= 1) { s += __shfl_xor(s, off); ss += __shfl_xor(ss, off); }
    const float m = s * (1.f / 160.f);
    const float rs = rsqrtf(ss * (1.f / 160.f) - m * m + 1e-5f);
    const float g = __shfl(twv, row);
    const _Float16* hr = h16 + (size_t)nodec * 160;
#pragma unroll
    for (int i = 0; i < 10; ++i) {
      int j = i * 16 + mrow;
      float hnew = fmaxf(fmaf((v[i] - m) * rs, gu[j], beu[j]), 0.f);
      float hold = (float)hr[j];
      tile[(w * 16 + row) * 168 + j] = (_Float16)fmaf(g, hnew - hold, hold);  // final h: LDS only
    }
  }
  // ---- phase 2: out = L2norm(tile @ Wo^T + b_out); 128 cols, K=160
  floatx4 acc2[8];
#pragma unroll
  for (int i = 0; i < 8; ++i) acc2[i] = (floatx4)0.f;
  int kbase = 0;
#pragma unroll 1
  for (int ks = 0; ks < 3; ++ks) {
    const int kw = (ks == 2) ? 32 : 64;
    __syncthreads();
    stage_B(Bsh, Wo, 160, kbase, 128, kw, t);
    __syncthreads();
    const int nkt = kw >> 5;
    for (int h2 = 0; h2 < nkt; ++h2) {
      half8 a = *(const half8*)&tile[(w * 16 + mrow) * 168 + kbase + h2 * 32 + quad * 8];
#pragma unroll
      for (int i = 0; i < 8; ++i) {
        half8 b = *(const half8*)&Bsh[(i * 16 + mrow) * 72 + h2 * 32 + quad * 8];
        acc2[i] = __builtin_amdgcn_mfma_f32_16x16x32_f16(a, b, acc2[i], 0, 0, 0);
      }
    }
    kbase += kw;
  }
#pragma unroll
  for (int r = 0; r < 4; ++r) {
    const int row = quad * 4 + r;
    const int node = n0 + w * 16 + row;
    float v[8], ss = 0.f;
#pragma unroll
    for (int i = 0; i < 8; ++i) {
      v[i] = acc2[i][r] + b_out[i * 16 + mrow];
      ss = fmaf(v[i], v[i], ss);
    }
#pragma unroll
    for (int off = 1; off < 16; off <<= 1) ss += __shfl_xor(ss, off);
    const float inv = 1.f / fmaxf(sqrtf(ss), 1e-12f);
    if (node < NN) {
#pragma unroll
      for (int i = 0; i < 8; ++i)
        out[(size_t)node * 128 + i * 16 + mrow] = v[i] * inv;
    }
  }
}

// ---------------------------------------------------------------- launch
extern "C" void kernel_launch(void* const* d_in, const int* in_sizes, int n_in,
                              void* d_out, int out_size, void* d_ws, size_t ws_size,
                              hipStream_t stream) {
  (void)in_sizes; (void)n_in; (void)out_size; (void)ws_size;
  const float* x       = (const float*)d_in[0];
  const int*   ei      = (const int*)  d_in[1];
  const float* ew      = (const float*)d_in[2];
  const float* tsp     = (const float*)d_in[3];
  const float* w_enc   = (const float*)d_in[4];
  const float* b_enc   = (const float*)d_in[5];
  const float* g_enc   = (const float*)d_in[6];
  const float* be_enc  = (const float*)d_in[7];
  const float* w_time  = (const float*)d_in[8];
  const float* b_time  = (const float*)d_in[9];
  const float* g_time  = (const float*)d_in[10];
  const float* be_time = (const float*)d_in[11];
  const float* wm      = (const float*)d_in[12];
  const float* bm      = (const float*)d_in[13];
  const float* gm      = (const float*)d_in[14];
  const float* bem     = (const float*)d_in[15];
  const float* wu      = (const float*)d_in[16];
  const float* bu      = (const float*)d_in[17];
  const float* gu      = (const float*)d_in[18];
  const float* beu     = (const float*)d_in[19];
  const float* wg      = (const float*)d_in[20];
  const float* bg      = (const float*)d_in[21];
  const float* w_out   = (const float*)d_in[22];
  const float* b_out   = (const float*)d_in[23];
  float* out = (float*)d_out;

  // ws layout (bytes): h16 f16[NN*160] @0 (32M) | msum16 f16[NN*160] @32,000,000 (32M)
  //   P f16[NN*320] @64,000,000 (64M) | Wu16 @128,000,000 (204,800) | Wo16 @128,204,800 (40,960)
  char* ws = (char*)d_ws;
  _Float16* h16     = (_Float16*)ws;
  _Float16* msum16  = (_Float16*)(ws + 32000000);
  _Float16* P       = (_Float16*)(ws + 64000000);
  _Float16* Wu16    = (_Float16*)(ws + 128000000);
  _Float16* Wo16    = (_Float16*)(ws + 128204800);
  // d_out doubles as scratch; k_update_out reads only ws-resident scratch.
  char* ob = (char*)d_out;
  _Float16* Wp16 = (_Float16*)ob;             // 204,800
  _Float16* We16 = (_Float16*)(ob + 204800);  // 32,768
  int* off    = (int*)(ob + 237568);          // 400,016
  int* cnti   = (int*)(ob + 637584);          // 400,000
  int* cursor = (int*)(ob + 1037584);         // 400,000
  int* bsum   = (int*)(ob + 1437584);         // 1,568
  int* bsum2  = (int*)(ob + 1439152);         // 1,568
  int2* selist = (int2*)(ob + 1440720);       // 6,400,000 -> 7,840,720 < 51,200,000

  // weight prep + CSR build (edges static across layers: build once)
  k_zero<<<dim3(98), dim3(256), 0, stream>>>((float4*)cnti, 25000);
  k_cast<<<dim3(400), dim3(256), 0, stream>>>(wu, Wu16, 102400);
  k_cast<<<dim3(64),  dim3(256), 0, stream>>>(w_enc, We16, 16384);
  k_cast<<<dim3(80),  dim3(256), 0, stream>>>(w_out, Wo16, 20480);
  k_prep_wm<<<dim3(400), dim3(256), 0, stream>>>(wm, Wp16);
  k_count_i<<<dim3(3125), dim3(256), 0, stream>>>(ei, cnti);
  k_scan1<<<dim3(391), dim3(256), 0, stream>>>(cnti, off, bsum);
  k_scan2<<<dim3(1), dim3(512), 0, stream>>>(bsum, bsum2);
  k_scan3<<<dim3(391), dim3(256), 0, stream>>>(off, bsum2, cursor);
  k_scatter<<<dim3(3125), dim3(256), 0, stream>>>(ei, ew, cursor, selist);

  k_encode_proj<<<dim3(1563), dim3(256), 0, stream>>>(
      x, tsp, We16, b_enc, g_enc, be_enc, w_time, b_time, g_time, be_time,
      Wp16, bm, h16, P);
  k_edge3<<<dim3(12500), dim3(256), 0, stream>>>(P, off, selist, gm, bem, msum16);
  k_update_proj<<<dim3(1563), dim3(256), 0, stream>>>(
      h16, msum16, Wu16, bu, gu, beu, wg, bg,
      Wp16 + 51200, bm + 160, P);
  k_edge3<<<dim3(12500), dim3(256), 0, stream>>>(P, off, selist, gm + 160, bem + 160, msum16);
  k_update_out<<<dim3(1563), dim3(256), 0, stream>>>(
      h16, msum16, Wu16 + 51200, bu + 160, gu + 160, beu + 160, wg + 160, bg + 1,
      Wo16, b_out, out);
}